// Round 10
// baseline (410.481 us; speedup 1.0000x reference)
//
#include <hip/hip_runtime.h>
#include <hip/hip_bf16.h>

// GATv2 x2 on MI355X — MFMA gemm1 (split-bf16), bf16 xl1 gather rows.
//  k_node1f is L2-miss-traffic-bound (R9: 280 MB @ ~3.5 TB/s = measured dur).
//  xl1 is consumed only by node1f -> store it bf16 straight from the MFMA
//  epilogue: gathered bytes halve (256 -> 128 B per edge-head), and the
//  10 MB array doubles its effective per-XCD L2 residency.
//  gemm2: W2 pre-transposed to Wt[64][512] so the inner loop is float4 loads.

constexpr int N_NODES = 10000;
constexpr int N_EDGES = 320000;
constexpr int ET      = N_EDGES + N_NODES;   // 330000 incl. self loops
constexpr float NEG_SLOPE = 0.2f;
constexpr int MAXD1 = 384;                   // LDS ssrc cache (layer1)
constexpr int MAXD2 = 160;                   // per node (layer2, 4 nodes/block)

typedef __attribute__((ext_vector_type(8))) short short8;
typedef __attribute__((ext_vector_type(8))) unsigned short ushort8_t;
typedef __attribute__((ext_vector_type(4))) float floatx4;

__device__ __forceinline__ float lrelu(float a) {
    return fmaxf(a, NEG_SLOPE * a);          // 0.2a > a iff a < 0
}
__device__ __forceinline__ unsigned short f2bf(float f) {   // RNE
    unsigned u = __float_as_uint(f);
    unsigned r = u + 0x7FFFu + ((u >> 16) & 1u);
    return (unsigned short)(r >> 16);
}
__device__ __forceinline__ float bf2f(unsigned short h) {
    return __uint_as_float((unsigned)h << 16);
}

// ---------------- CSR build ----------------

__global__ void k_count(const int* __restrict__ ei, int* __restrict__ deg) {
    int e = blockIdx.x * 256 + threadIdx.x;
    if (e >= ET) return;
    int d = (e < N_EDGES) ? ei[N_EDGES + e] : (e - N_EDGES);
    atomicAdd(&deg[d], 1);
}

__global__ __launch_bounds__(1024) void k_scan(const int* __restrict__ deg,
                                               int* __restrict__ offs) {
    __shared__ int part[1024];
    const int CH = 10;                       // ceil(10000/1024)
    int t = threadIdx.x;
    int base = t * CH;
    int loc[CH];
    int s = 0;
    for (int i = 0; i < CH; ++i) {
        int idx = base + i;
        int v = (idx < N_NODES) ? deg[idx] : 0;
        loc[i] = s; s += v;
    }
    part[t] = s;
    __syncthreads();
    for (int o = 1; o < 1024; o <<= 1) {
        int add = (t >= o) ? part[t - o] : 0;
        __syncthreads();
        part[t] += add;
        __syncthreads();
    }
    int excl = part[t] - s;
    for (int i = 0; i < CH; ++i) {
        int idx = base + i;
        if (idx < N_NODES) offs[idx] = excl + loc[i];
    }
    if (t == 1023) offs[N_NODES] = part[1023];
}

__global__ void k_scatter(const int* __restrict__ ei, const int* __restrict__ offs,
                          int* __restrict__ cursor, int* __restrict__ ssrc) {
    int e = blockIdx.x * 256 + threadIdx.x;
    if (e >= ET) return;
    int s, d;
    if (e < N_EDGES) { s = ei[e]; d = ei[N_EDGES + e]; }
    else             { s = d = e - N_EDGES; }
    int pos = offs[d] + atomicAdd(&cursor[d], 1);
    ssrc[pos] = s;
}

// ---------------- layer 1: split-bf16 conversion + MFMA GEMM ----------------

// x[10000,256] fp32 -> A'[10000,768] bf16: segs [hi | lo | hi]
__global__ __launch_bounds__(256) void k_conv_x(const float* __restrict__ x,
        unsigned short* __restrict__ A) {
    int idx = blockIdx.x * 256 + threadIdx.x;       // N_NODES*64 threads
    if (idx >= N_NODES * 64) return;
    int m = idx >> 6, kg = (idx & 63) << 2;
    float4 v = *reinterpret_cast<const float4*>(x + (size_t)m * 256 + kg);
    ushort4 hi = make_ushort4(f2bf(v.x), f2bf(v.y), f2bf(v.z), f2bf(v.w));
    ushort4 lo = make_ushort4(f2bf(v.x - bf2f(hi.x)), f2bf(v.y - bf2f(hi.y)),
                              f2bf(v.z - bf2f(hi.z)), f2bf(v.w - bf2f(hi.w)));
    size_t base = (size_t)m * 768 + kg;
    *reinterpret_cast<ushort4*>(A + base)       = hi;
    *reinterpret_cast<ushort4*>(A + base + 256) = lo;
    *reinterpret_cast<ushort4*>(A + base + 512) = hi;
}

// W1l/W1r [256,512] fp32 -> Bt[1024,768] bf16 (transposed): segs [hi | hi | lo]
__global__ __launch_bounds__(256) void k_conv_w(const float* __restrict__ Wl,
        const float* __restrict__ Wr, unsigned short* __restrict__ Bt) {
    int idx = blockIdx.x * 256 + threadIdx.x;       // 1024*64 threads
    if (idx >= 1024 * 64) return;
    int n = idx >> 6, kg = (idx & 63) << 2;
    const float* src = (n < 512) ? (Wl + n) : (Wr + (n - 512));
    float v0 = src[(size_t)(kg + 0) * 512];
    float v1 = src[(size_t)(kg + 1) * 512];
    float v2 = src[(size_t)(kg + 2) * 512];
    float v3 = src[(size_t)(kg + 3) * 512];
    ushort4 hi = make_ushort4(f2bf(v0), f2bf(v1), f2bf(v2), f2bf(v3));
    ushort4 lo = make_ushort4(f2bf(v0 - bf2f(hi.x)), f2bf(v1 - bf2f(hi.y)),
                              f2bf(v2 - bf2f(hi.z)), f2bf(v3 - bf2f(hi.w)));
    size_t base = (size_t)n * 768 + kg;
    *reinterpret_cast<ushort4*>(Bt + base)       = hi;
    *reinterpret_cast<ushort4*>(Bt + base + 256) = hi;
    *reinterpret_cast<ushort4*>(Bt + base + 512) = lo;
}

// W2l/W2r [512,32] fp32 -> Wt[64,512] fp32 (transposed, fused l|r)
__global__ __launch_bounds__(256) void k_conv_w2(const float* __restrict__ Wl,
        const float* __restrict__ Wr, float* __restrict__ Wt) {
    int idx = blockIdx.x * 256 + threadIdx.x;       // 64*512 threads
    if (idx >= 64 * 512) return;
    int j = idx >> 9, k = idx & 511;
    float v = (j < 32) ? Wl[(size_t)k * 32 + j] : Wr[(size_t)k * 32 + (j - 32)];
    Wt[(size_t)j * 512 + k] = v;
}

// 128x128 tile MFMA GEMM, M=10000 N=1024 K=768, grid (79,8), 4 waves/block.
// Columns <512 (xl) stored as bf16; columns >=512 (xr) stored fp32.
__global__ __launch_bounds__(256) void k_mfma1(const unsigned short* __restrict__ A,
        const unsigned short* __restrict__ Bt, unsigned short* __restrict__ xl1b,
        float* __restrict__ xr1) {
    __shared__ unsigned short As[128 * 40];   // stride 40 (80B): 2-way max = free
    __shared__ unsigned short Bs[128 * 40];
    int t = threadIdx.x;
    int wave = t >> 6, L = t & 63;
    int wm = wave & 1, wn = wave >> 1;
    int row0 = blockIdx.x * 128, n0 = blockIdx.y * 128;
    int q = L >> 4, rr = L & 15;
    floatx4 acc[4][4];
#pragma unroll
    for (int i = 0; i < 4; ++i)
#pragma unroll
        for (int j = 0; j < 4; ++j) acc[i][j] = (floatx4){0.f, 0.f, 0.f, 0.f};
    int ra = t >> 2,        ka = (t & 3) * 8;
    int rb = (t + 256) >> 2, kb = ((t + 256) & 3) * 8;
    int gma = row0 + ra; gma = (gma < N_NODES) ? gma : (N_NODES - 1);
    int gmb = row0 + rb; gmb = (gmb < N_NODES) ? gmb : (N_NODES - 1);
    for (int kc = 0; kc < 768; kc += 32) {
        __syncthreads();
        *reinterpret_cast<uint4*>(&As[ra * 40 + ka]) =
            *reinterpret_cast<const uint4*>(A + (size_t)gma * 768 + kc + ka);
        *reinterpret_cast<uint4*>(&As[rb * 40 + kb]) =
            *reinterpret_cast<const uint4*>(A + (size_t)gmb * 768 + kc + kb);
        *reinterpret_cast<uint4*>(&Bs[ra * 40 + ka]) =
            *reinterpret_cast<const uint4*>(Bt + (size_t)(n0 + ra) * 768 + kc + ka);
        *reinterpret_cast<uint4*>(&Bs[rb * 40 + kb]) =
            *reinterpret_cast<const uint4*>(Bt + (size_t)(n0 + rb) * 768 + kc + kb);
        __syncthreads();
        short8 af[4], bf[4];
#pragma unroll
        for (int st = 0; st < 4; ++st)
            af[st] = *reinterpret_cast<const short8*>(
                &As[(wm * 64 + st * 16 + rr) * 40 + q * 8]);
#pragma unroll
        for (int st = 0; st < 4; ++st)
            bf[st] = *reinterpret_cast<const short8*>(
                &Bs[(wn * 64 + st * 16 + rr) * 40 + q * 8]);
#pragma unroll
        for (int i = 0; i < 4; ++i)
#pragma unroll
            for (int j = 0; j < 4; ++j)
                acc[i][j] = __builtin_amdgcn_mfma_f32_16x16x32_bf16(
                    af[i], bf[j], acc[i][j], 0, 0, 0);
    }
    // epilogue: C/D layout col=lane&15, row=(lane>>4)*4+reg  [m89/m91]
#pragma unroll
    for (int j = 0; j < 4; ++j) {
        int gc = n0 + wn * 64 + j * 16 + rr;
        if (gc < 512) {
#pragma unroll
            for (int i = 0; i < 4; ++i)
#pragma unroll
                for (int r = 0; r < 4; ++r) {
                    int gr = row0 + wm * 64 + i * 16 + q * 4 + r;
                    if (gr < N_NODES)
                        xl1b[(size_t)gr * 512 + gc] = f2bf(acc[i][j][r]);
                }
        } else {
            int col = gc - 512;
#pragma unroll
            for (int i = 0; i < 4; ++i)
#pragma unroll
                for (int r = 0; r < 4; ++r) {
                    int gr = row0 + wm * 64 + i * 16 + q * 4 + r;
                    if (gr < N_NODES)
                        xr1[(size_t)gr * 512 + col] = acc[i][j][r];
                }
        }
    }
}

// Fused edge+node layer 1: one block (512 thr = 8 waves) per node; wave = head.
// Lane (ej,cg): bf16 row gather (16 B), own edge-slot accumulation, prefetched.
__global__ __launch_bounds__(512) void k_node1f(const int* __restrict__ offs,
        const int* __restrict__ ssrc, const unsigned short* __restrict__ xl1b,
        const float* __restrict__ xr1, const float* __restrict__ att1,
        const float* __restrict__ b1, float* __restrict__ h1) {
    constexpr int C = 8;                 // edges per chunk
    __shared__ int slds[MAXD1];
    int n = blockIdx.x;
    int t = threadIdx.x;                 // t = h*64 + lane
    int h = t >> 6, lane = t & 63;
    int beg = offs[n], dcnt = offs[n + 1] - beg;
    int cap = (dcnt < MAXD1) ? dcnt : MAXD1;
    for (int i = t; i < cap; i += 512) slds[i] = ssrc[beg + i];
    __syncthreads();
    int ej = lane >> 3;                  // edge slot within chunk
    int cg = lane & 7;                   // channel group of 8
    float xrv[8], atv[8];
    {
        const float* xrrow = xr1 + (size_t)n * 512 + h * 64 + cg * 8;
        const float* atrow = att1 + h * 64 + cg * 8;
#pragma unroll
        for (int i = 0; i < 8; ++i) { xrv[i] = xrrow[i]; atv[i] = atrow[i]; }
    }
    float l = 0.f;
    float acc8[8];
#pragma unroll
    for (int i = 0; i < 8; ++i) acc8[i] = 0.f;

    auto fetch = [&](int base, ushort8_t& u) {
        int i1 = base + ej;
        int i1c = (i1 < dcnt) ? i1 : (dcnt - 1);       // dup row; w=0 masks
        int sj = (i1c < MAXD1) ? slds[i1c] : ssrc[beg + i1c];
        u = *reinterpret_cast<const ushort8_t*>(
                xl1b + (size_t)sj * 512 + h * 64 + cg * 8);
    };
    ushort8_t ux;
    fetch(0, ux);
    for (int base = 0; base < dcnt; base += C) {
        ushort8_t un;
        fetch(base + C < dcnt ? base + C : base, un);  // dbuf prefetch
        float xs[8];
#pragma unroll
        for (int i = 0; i < 8; ++i) xs[i] = bf2f(ux[i]);
        float p = 0.f;
#pragma unroll
        for (int i = 0; i < 8; ++i) p += lrelu(xs[i] + xrv[i]) * atv[i];
        p += __shfl_xor(p, 1);
        p += __shfl_xor(p, 2);
        p += __shfl_xor(p, 4);           // own edge's alpha in all 8 cg lanes
        if (base + ej >= dcnt) p = -1e30f;
        float w = __expf(fminf(p, 60.f));    // exp(-1e30) = 0
        l += w;
#pragma unroll
        for (int i = 0; i < 8; ++i) acc8[i] += w * xs[i];
        ux = un;
    }
    // reduce over the 8 edge slots (once per node)
#pragma unroll
    for (int o = 8; o < 64; o <<= 1) {
        l += __shfl_xor(l, o);
#pragma unroll
        for (int i = 0; i < 8; ++i) acc8[i] += __shfl_xor(acc8[i], o);
    }
    float inv = 1.f / (l + 1e-16f);
    float v8[8];
    {
        const float* brow = b1 + h * 64 + cg * 8;
#pragma unroll
        for (int i = 0; i < 8; ++i) {
            float v = acc8[i] * inv + brow[i];
            v8[i] = (v > 0.f) ? v : expm1f(v);   // elu
        }
    }
    if (ej == 0) {
        float4 va = {v8[0], v8[1], v8[2], v8[3]};
        float4 vb = {v8[4], v8[5], v8[6], v8[7]};
        float* dst = h1 + (size_t)n * 512 + h * 64 + cg * 8;
        *reinterpret_cast<float4*>(dst)     = va;
        *reinterpret_cast<float4*>(dst + 4) = vb;
    }
}

// ---------------- layer 2 ----------------

// 4 rows x 64 cols per block, 256 threads; W pre-transposed (Wt[64][512]).
__global__ __launch_bounds__(256) void k_gemm2(const float* __restrict__ h1,
        const float* __restrict__ Wt, float* __restrict__ xw2) {
    __shared__ float hs[4 * 512];
    int t = threadIdx.x;
    int n0 = blockIdx.x * 4;
    const float4* hsrc = reinterpret_cast<const float4*>(h1 + (size_t)n0 * 512);
    float4* hdst = reinterpret_cast<float4*>(hs);
    for (int i = t; i < 512; i += 256) hdst[i] = hsrc[i];
    __syncthreads();
    int r = t >> 6, j = t & 63;
    const float* Wrow = Wt + (size_t)j * 512;
    float acc = 0.f;
    for (int k = 0; k < 512; k += 8) {
        float4 a0 = *reinterpret_cast<const float4*>(&hs[r * 512 + k]);
        float4 a1 = *reinterpret_cast<const float4*>(&hs[r * 512 + k + 4]);
        float4 w0 = *reinterpret_cast<const float4*>(Wrow + k);
        float4 w1 = *reinterpret_cast<const float4*>(Wrow + k + 4);
        acc += a0.x * w0.x + a0.y * w0.y + a0.z * w0.z + a0.w * w0.w
             + a1.x * w1.x + a1.y * w1.y + a1.z * w1.z + a1.w * w1.w;
    }
    xw2[(size_t)(n0 + r) * 64 + j] = acc;
}

// Fused edge+node layer 2 + log_softmax: one wave per node (4 nodes/block).
// Lane (ej, cg) owns 4 channels; no online rescale; prefetched.
__global__ __launch_bounds__(256) void k_node2f(const int* __restrict__ offs,
        const int* __restrict__ ssrc, const float* __restrict__ xw2,
        const float* __restrict__ att2, const float* __restrict__ b2,
        float* __restrict__ out) {
    constexpr int C = 8;
    __shared__ int slds[4 * MAXD2];
    int t = threadIdx.x;
    int wv = t >> 6;
    int n = blockIdx.x * 4 + wv;
    int lane = t & 63;
    int beg = offs[n], dcnt = offs[n + 1] - beg;
    int cap = (dcnt < MAXD2) ? dcnt : MAXD2;
    int* sl = slds + wv * MAXD2;
    for (int i = lane; i < cap; i += 64) sl[i] = ssrc[beg + i];
    __syncthreads();
    int ej = lane >> 3;                  // edge slot
    int cg = lane & 7;                   // channel group of 4
    float4 xr = *reinterpret_cast<const float4*>(xw2 + (size_t)n * 64 + 32 + cg * 4);
    float4 at = *reinterpret_cast<const float4*>(att2 + cg * 4);
    float l = 0.f;
    float4 ac = {0.f, 0.f, 0.f, 0.f};
    auto fetch = [&](int base, float4& xa) {
        int i1 = base + ej;
        int i1c = (i1 < dcnt) ? i1 : (dcnt - 1);
        int sj = (i1c < MAXD2) ? sl[i1c] : ssrc[beg + i1c];
        xa = *reinterpret_cast<const float4*>(xw2 + (size_t)sj * 64 + cg * 4);
    };
    float4 xa;
    fetch(0, xa);
    for (int base = 0; base < dcnt; base += C) {
        float4 na;
        fetch(base + C < dcnt ? base + C : base, na);
        float p = lrelu(xa.x + xr.x) * at.x + lrelu(xa.y + xr.y) * at.y
                + lrelu(xa.z + xr.z) * at.z + lrelu(xa.w + xr.w) * at.w;
        p += __shfl_xor(p, 1);
        p += __shfl_xor(p, 2);
        p += __shfl_xor(p, 4);
        if (base + ej >= dcnt) p = -1e30f;
        float w = __expf(fminf(p, 60.f));
        l += w;
        ac.x += w * xa.x; ac.y += w * xa.y;
        ac.z += w * xa.z; ac.w += w * xa.w;
        xa = na;
    }
#pragma unroll
    for (int o = 8; o < 64; o <<= 1) {
        l    += __shfl_xor(l, o);
        ac.x += __shfl_xor(ac.x, o); ac.y += __shfl_xor(ac.y, o);
        ac.z += __shfl_xor(ac.z, o); ac.w += __shfl_xor(ac.w, o);
    }
    float inv = 1.f / (l + 1e-16f);
    float4 bb = *reinterpret_cast<const float4*>(b2 + cg * 4);
    float4 v;
    v.x = ac.x * inv + bb.x; v.y = ac.y * inv + bb.y;
    v.z = ac.z * inv + bb.z; v.w = ac.w * inv + bb.w;
    // log_softmax over 32 channels: local max/sum over 4, then across cg
    float mx = fmaxf(fmaxf(v.x, v.y), fmaxf(v.z, v.w));
    mx = fmaxf(mx, __shfl_xor(mx, 1));
    mx = fmaxf(mx, __shfl_xor(mx, 2));
    mx = fmaxf(mx, __shfl_xor(mx, 4));
    float se = __expf(v.x - mx) + __expf(v.y - mx)
             + __expf(v.z - mx) + __expf(v.w - mx);
    se += __shfl_xor(se, 1);
    se += __shfl_xor(se, 2);
    se += __shfl_xor(se, 4);
    float ls = __logf(se);
    v.x = v.x - mx - ls; v.y = v.y - mx - ls;
    v.z = v.z - mx - ls; v.w = v.w - mx - ls;
    if (ej == 0)
        *reinterpret_cast<float4*>(out + (size_t)n * 32 + cg * 4) = v;
}

// ---------------- launch ----------------

extern "C" void kernel_launch(void* const* d_in, const int* in_sizes, int n_in,
                              void* d_out, int out_size, void* d_ws, size_t ws_size,
                              hipStream_t stream) {
    (void)in_sizes; (void)n_in; (void)out_size; (void)ws_size;
    const float* x    = (const float*)d_in[0];
    const int*   ei   = (const int*)d_in[1];
    const float* W1l  = (const float*)d_in[2];
    const float* W1r  = (const float*)d_in[3];
    const float* att1 = (const float*)d_in[4];
    const float* b1   = (const float*)d_in[5];
    const float* W2l  = (const float*)d_in[6];
    const float* W2r  = (const float*)d_in[7];
    const float* att2 = (const float*)d_in[8];
    const float* b2   = (const float*)d_in[9];
    float* outp = (float*)d_out;

    char* ws = (char*)d_ws;
    size_t o = 0;
    auto alloc = [&](size_t bytes) {
        char* p = ws + o;
        o = (o + bytes + 255) & ~(size_t)255;
        return p;
    };
    unsigned short* xl1b = (unsigned short*)alloc((size_t)N_NODES * 512 * 2);
    float* xr1    = (float*)alloc((size_t)N_NODES * 512 * 4);
    float* h1     = (float*)alloc((size_t)N_NODES * 512 * 4);
    float* xw2    = (float*)alloc((size_t)N_NODES * 64 * 4);
    float* Wt     = (float*)alloc((size_t)64 * 512 * 4);
    unsigned short* Abf = (unsigned short*)alloc((size_t)N_NODES * 768 * 2);
    unsigned short* Bbf = (unsigned short*)alloc((size_t)1024 * 768 * 2);
    int*   deg    = (int*)alloc((size_t)N_NODES * 4);
    int*   cursor = (int*)alloc((size_t)N_NODES * 4);
    int*   offs   = (int*)alloc((size_t)(N_NODES + 1) * 4);
    int*   ssrc   = (int*)alloc((size_t)ET * 4);

    hipMemsetAsync(deg, 0, (size_t)N_NODES * 4, stream);
    hipMemsetAsync(cursor, 0, (size_t)N_NODES * 4, stream);

    k_count  <<<(ET + 255) / 256,      256, 0, stream>>>(ei, deg);
    k_scan   <<<1,                    1024, 0, stream>>>(deg, offs);
    k_scatter<<<(ET + 255) / 256,      256, 0, stream>>>(ei, offs, cursor, ssrc);
    k_conv_x <<<(N_NODES * 64 + 255) / 256, 256, 0, stream>>>(x, Abf);
    k_conv_w <<<(1024 * 64 + 255) / 256,    256, 0, stream>>>(W1l, W1r, Bbf);
    k_conv_w2<<<(64 * 512 + 255) / 256,     256, 0, stream>>>(W2l, W2r, Wt);
    k_mfma1  <<<dim3(79, 8),           256, 0, stream>>>(Abf, Bbf, xl1b, xr1);
    k_node1f <<<N_NODES,               512, 0, stream>>>(offs, ssrc, xl1b, xr1, att1, b1, h1);
    k_gemm2  <<<N_NODES / 4,           256, 0, stream>>>(h1, Wt, xw2);
    k_node2f <<<N_NODES / 4,           256, 0, stream>>>(offs, ssrc, xw2, att2, b2, outp);
}

// Round 11
// 301.074 us; speedup vs baseline: 1.3634x; 1.3634x over previous
//
#include <hip/hip_runtime.h>
#include <hip/hip_bf16.h>

// GATv2 x2 on MI355X — MFMA gemm1 (split-bf16), bf16 xl1 gather rows (R10 win),
// gemm2 reverted to lane-coalesced W columns + 8-rows-per-wave amortization
// (R10's transposed-W was anti-coalesced across lanes: 148 us @ 8.7% VALU).

constexpr int N_NODES = 10000;
constexpr int N_EDGES = 320000;
constexpr int ET      = N_EDGES + N_NODES;   // 330000 incl. self loops
constexpr float NEG_SLOPE = 0.2f;
constexpr int MAXD1 = 384;                   // LDS ssrc cache (layer1)
constexpr int MAXD2 = 160;                   // per node (layer2, 4 nodes/block)

typedef __attribute__((ext_vector_type(8))) short short8;
typedef __attribute__((ext_vector_type(8))) unsigned short ushort8_t;
typedef __attribute__((ext_vector_type(4))) float floatx4;

__device__ __forceinline__ float lrelu(float a) {
    return fmaxf(a, NEG_SLOPE * a);          // 0.2a > a iff a < 0
}
__device__ __forceinline__ unsigned short f2bf(float f) {   // RNE
    unsigned u = __float_as_uint(f);
    unsigned r = u + 0x7FFFu + ((u >> 16) & 1u);
    return (unsigned short)(r >> 16);
}
__device__ __forceinline__ float bf2f(unsigned short h) {
    return __uint_as_float((unsigned)h << 16);
}

// ---------------- CSR build ----------------

__global__ void k_count(const int* __restrict__ ei, int* __restrict__ deg) {
    int e = blockIdx.x * 256 + threadIdx.x;
    if (e >= ET) return;
    int d = (e < N_EDGES) ? ei[N_EDGES + e] : (e - N_EDGES);
    atomicAdd(&deg[d], 1);
}

__global__ __launch_bounds__(1024) void k_scan(const int* __restrict__ deg,
                                               int* __restrict__ offs) {
    __shared__ int part[1024];
    const int CH = 10;                       // ceil(10000/1024)
    int t = threadIdx.x;
    int base = t * CH;
    int loc[CH];
    int s = 0;
    for (int i = 0; i < CH; ++i) {
        int idx = base + i;
        int v = (idx < N_NODES) ? deg[idx] : 0;
        loc[i] = s; s += v;
    }
    part[t] = s;
    __syncthreads();
    for (int o = 1; o < 1024; o <<= 1) {
        int add = (t >= o) ? part[t - o] : 0;
        __syncthreads();
        part[t] += add;
        __syncthreads();
    }
    int excl = part[t] - s;
    for (int i = 0; i < CH; ++i) {
        int idx = base + i;
        if (idx < N_NODES) offs[idx] = excl + loc[i];
    }
    if (t == 1023) offs[N_NODES] = part[1023];
}

__global__ void k_scatter(const int* __restrict__ ei, const int* __restrict__ offs,
                          int* __restrict__ cursor, int* __restrict__ ssrc) {
    int e = blockIdx.x * 256 + threadIdx.x;
    if (e >= ET) return;
    int s, d;
    if (e < N_EDGES) { s = ei[e]; d = ei[N_EDGES + e]; }
    else             { s = d = e - N_EDGES; }
    int pos = offs[d] + atomicAdd(&cursor[d], 1);
    ssrc[pos] = s;
}

// ---------------- layer 1: split-bf16 conversion + MFMA GEMM ----------------

// x[10000,256] fp32 -> A'[10000,768] bf16: segs [hi | lo | hi]
__global__ __launch_bounds__(256) void k_conv_x(const float* __restrict__ x,
        unsigned short* __restrict__ A) {
    int idx = blockIdx.x * 256 + threadIdx.x;       // N_NODES*64 threads
    if (idx >= N_NODES * 64) return;
    int m = idx >> 6, kg = (idx & 63) << 2;
    float4 v = *reinterpret_cast<const float4*>(x + (size_t)m * 256 + kg);
    ushort4 hi = make_ushort4(f2bf(v.x), f2bf(v.y), f2bf(v.z), f2bf(v.w));
    ushort4 lo = make_ushort4(f2bf(v.x - bf2f(hi.x)), f2bf(v.y - bf2f(hi.y)),
                              f2bf(v.z - bf2f(hi.z)), f2bf(v.w - bf2f(hi.w)));
    size_t base = (size_t)m * 768 + kg;
    *reinterpret_cast<ushort4*>(A + base)       = hi;
    *reinterpret_cast<ushort4*>(A + base + 256) = lo;
    *reinterpret_cast<ushort4*>(A + base + 512) = hi;
}

// W1l/W1r [256,512] fp32 -> Bt[1024,768] bf16 (transposed): segs [hi | hi | lo]
__global__ __launch_bounds__(256) void k_conv_w(const float* __restrict__ Wl,
        const float* __restrict__ Wr, unsigned short* __restrict__ Bt) {
    int idx = blockIdx.x * 256 + threadIdx.x;       // 1024*64 threads
    if (idx >= 1024 * 64) return;
    int n = idx >> 6, kg = (idx & 63) << 2;
    const float* src = (n < 512) ? (Wl + n) : (Wr + (n - 512));
    float v0 = src[(size_t)(kg + 0) * 512];
    float v1 = src[(size_t)(kg + 1) * 512];
    float v2 = src[(size_t)(kg + 2) * 512];
    float v3 = src[(size_t)(kg + 3) * 512];
    ushort4 hi = make_ushort4(f2bf(v0), f2bf(v1), f2bf(v2), f2bf(v3));
    ushort4 lo = make_ushort4(f2bf(v0 - bf2f(hi.x)), f2bf(v1 - bf2f(hi.y)),
                              f2bf(v2 - bf2f(hi.z)), f2bf(v3 - bf2f(hi.w)));
    size_t base = (size_t)n * 768 + kg;
    *reinterpret_cast<ushort4*>(Bt + base)       = hi;
    *reinterpret_cast<ushort4*>(Bt + base + 256) = hi;
    *reinterpret_cast<ushort4*>(Bt + base + 512) = lo;
}

// 128x128 tile MFMA GEMM, M=10000 N=1024 K=768, grid (79,8), 4 waves/block.
// Columns <512 (xl) stored as bf16; columns >=512 (xr) stored fp32.
__global__ __launch_bounds__(256) void k_mfma1(const unsigned short* __restrict__ A,
        const unsigned short* __restrict__ Bt, unsigned short* __restrict__ xl1b,
        float* __restrict__ xr1) {
    __shared__ unsigned short As[128 * 40];   // stride 40 (80B): 2-way max = free
    __shared__ unsigned short Bs[128 * 40];
    int t = threadIdx.x;
    int wave = t >> 6, L = t & 63;
    int wm = wave & 1, wn = wave >> 1;
    int row0 = blockIdx.x * 128, n0 = blockIdx.y * 128;
    int q = L >> 4, rr = L & 15;
    floatx4 acc[4][4];
#pragma unroll
    for (int i = 0; i < 4; ++i)
#pragma unroll
        for (int j = 0; j < 4; ++j) acc[i][j] = (floatx4){0.f, 0.f, 0.f, 0.f};
    int ra = t >> 2,        ka = (t & 3) * 8;
    int rb = (t + 256) >> 2, kb = ((t + 256) & 3) * 8;
    int gma = row0 + ra; gma = (gma < N_NODES) ? gma : (N_NODES - 1);
    int gmb = row0 + rb; gmb = (gmb < N_NODES) ? gmb : (N_NODES - 1);
    for (int kc = 0; kc < 768; kc += 32) {
        __syncthreads();
        *reinterpret_cast<uint4*>(&As[ra * 40 + ka]) =
            *reinterpret_cast<const uint4*>(A + (size_t)gma * 768 + kc + ka);
        *reinterpret_cast<uint4*>(&As[rb * 40 + kb]) =
            *reinterpret_cast<const uint4*>(A + (size_t)gmb * 768 + kc + kb);
        *reinterpret_cast<uint4*>(&Bs[ra * 40 + ka]) =
            *reinterpret_cast<const uint4*>(Bt + (size_t)(n0 + ra) * 768 + kc + ka);
        *reinterpret_cast<uint4*>(&Bs[rb * 40 + kb]) =
            *reinterpret_cast<const uint4*>(Bt + (size_t)(n0 + rb) * 768 + kc + kb);
        __syncthreads();
        short8 af[4], bf[4];
#pragma unroll
        for (int st = 0; st < 4; ++st)
            af[st] = *reinterpret_cast<const short8*>(
                &As[(wm * 64 + st * 16 + rr) * 40 + q * 8]);
#pragma unroll
        for (int st = 0; st < 4; ++st)
            bf[st] = *reinterpret_cast<const short8*>(
                &Bs[(wn * 64 + st * 16 + rr) * 40 + q * 8]);
#pragma unroll
        for (int i = 0; i < 4; ++i)
#pragma unroll
            for (int j = 0; j < 4; ++j)
                acc[i][j] = __builtin_amdgcn_mfma_f32_16x16x32_bf16(
                    af[i], bf[j], acc[i][j], 0, 0, 0);
    }
    // epilogue: C/D layout col=lane&15, row=(lane>>4)*4+reg  [m89/m91]
#pragma unroll
    for (int j = 0; j < 4; ++j) {
        int gc = n0 + wn * 64 + j * 16 + rr;
        if (gc < 512) {
#pragma unroll
            for (int i = 0; i < 4; ++i)
#pragma unroll
                for (int r = 0; r < 4; ++r) {
                    int gr = row0 + wm * 64 + i * 16 + q * 4 + r;
                    if (gr < N_NODES)
                        xl1b[(size_t)gr * 512 + gc] = f2bf(acc[i][j][r]);
                }
        } else {
            int col = gc - 512;
#pragma unroll
            for (int i = 0; i < 4; ++i)
#pragma unroll
                for (int r = 0; r < 4; ++r) {
                    int gr = row0 + wm * 64 + i * 16 + q * 4 + r;
                    if (gr < N_NODES)
                        xr1[(size_t)gr * 512 + col] = acc[i][j][r];
                }
        }
    }
}

// Fused edge+node layer 1: one block (512 thr = 8 waves) per node; wave = head.
// Lane (ej,cg): bf16 row gather (16 B), own edge-slot accumulation, prefetched.
__global__ __launch_bounds__(512) void k_node1f(const int* __restrict__ offs,
        const int* __restrict__ ssrc, const unsigned short* __restrict__ xl1b,
        const float* __restrict__ xr1, const float* __restrict__ att1,
        const float* __restrict__ b1, float* __restrict__ h1) {
    constexpr int C = 8;                 // edges per chunk
    __shared__ int slds[MAXD1];
    int n = blockIdx.x;
    int t = threadIdx.x;                 // t = h*64 + lane
    int h = t >> 6, lane = t & 63;
    int beg = offs[n], dcnt = offs[n + 1] - beg;
    int cap = (dcnt < MAXD1) ? dcnt : MAXD1;
    for (int i = t; i < cap; i += 512) slds[i] = ssrc[beg + i];
    __syncthreads();
    int ej = lane >> 3;                  // edge slot within chunk
    int cg = lane & 7;                   // channel group of 8
    float xrv[8], atv[8];
    {
        const float* xrrow = xr1 + (size_t)n * 512 + h * 64 + cg * 8;
        const float* atrow = att1 + h * 64 + cg * 8;
#pragma unroll
        for (int i = 0; i < 8; ++i) { xrv[i] = xrrow[i]; atv[i] = atrow[i]; }
    }
    float l = 0.f;
    float acc8[8];
#pragma unroll
    for (int i = 0; i < 8; ++i) acc8[i] = 0.f;

    auto fetch = [&](int base, ushort8_t& u) {
        int i1 = base + ej;
        int i1c = (i1 < dcnt) ? i1 : (dcnt - 1);       // dup row; w=0 masks
        int sj = (i1c < MAXD1) ? slds[i1c] : ssrc[beg + i1c];
        u = *reinterpret_cast<const ushort8_t*>(
                xl1b + (size_t)sj * 512 + h * 64 + cg * 8);
    };
    ushort8_t ux;
    fetch(0, ux);
    for (int base = 0; base < dcnt; base += C) {
        ushort8_t un;
        fetch(base + C < dcnt ? base + C : base, un);  // dbuf prefetch
        float xs[8];
#pragma unroll
        for (int i = 0; i < 8; ++i) xs[i] = bf2f(ux[i]);
        float p = 0.f;
#pragma unroll
        for (int i = 0; i < 8; ++i) p += lrelu(xs[i] + xrv[i]) * atv[i];
        p += __shfl_xor(p, 1);
        p += __shfl_xor(p, 2);
        p += __shfl_xor(p, 4);           // own edge's alpha in all 8 cg lanes
        if (base + ej >= dcnt) p = -1e30f;
        float w = __expf(fminf(p, 60.f));    // exp(-1e30) = 0
        l += w;
#pragma unroll
        for (int i = 0; i < 8; ++i) acc8[i] += w * xs[i];
        ux = un;
    }
    // reduce over the 8 edge slots (once per node)
#pragma unroll
    for (int o = 8; o < 64; o <<= 1) {
        l += __shfl_xor(l, o);
#pragma unroll
        for (int i = 0; i < 8; ++i) acc8[i] += __shfl_xor(acc8[i], o);
    }
    float inv = 1.f / (l + 1e-16f);
    float v8[8];
    {
        const float* brow = b1 + h * 64 + cg * 8;
#pragma unroll
        for (int i = 0; i < 8; ++i) {
            float v = acc8[i] * inv + brow[i];
            v8[i] = (v > 0.f) ? v : expm1f(v);   // elu
        }
    }
    if (ej == 0) {
        float4 va = {v8[0], v8[1], v8[2], v8[3]};
        float4 vb = {v8[4], v8[5], v8[6], v8[7]};
        float* dst = h1 + (size_t)n * 512 + h * 64 + cg * 8;
        *reinterpret_cast<float4*>(dst)     = va;
        *reinterpret_cast<float4*>(dst + 4) = vb;
    }
}

// ---------------- layer 2 ----------------

// 32 rows x 64 cols per block, 256 thr = 4 waves; wave owns 8 rows.
// Lane j reads W column j (coalesced across lanes: Wl+j / Wr+j-32, stride 32);
// h1 rows staged in LDS, read as wave-broadcast b128 (conflict-free).
__global__ __launch_bounds__(256) void k_gemm2(const float* __restrict__ h1,
        const float* __restrict__ Wl, const float* __restrict__ Wr,
        float* __restrict__ xw2) {
    __shared__ float hs[32 * 512];       // 64 KB
    int t = threadIdx.x;
    int wave = t >> 6, j = t & 63;
    int n0 = blockIdx.x * 32;
    // stage 32 rows (clamped for the tail block)
    {
        float4* hdst = reinterpret_cast<float4*>(hs);
        for (int i = t; i < 32 * 128; i += 256) {
            int rrow = i >> 7;
            int grow = n0 + rrow;
            grow = (grow < N_NODES) ? grow : (N_NODES - 1);
            hdst[i] = reinterpret_cast<const float4*>(
                          h1 + (size_t)grow * 512)[i & 127];
        }
    }
    __syncthreads();
    const float* W = (j < 32) ? (Wl + j) : (Wr + (j - 32));
    float acc[8];
#pragma unroll
    for (int r = 0; r < 8; ++r) acc[r] = 0.f;
    for (int k = 0; k < 512; k += 4) {
        float w0 = W[(size_t)(k + 0) * 32];
        float w1 = W[(size_t)(k + 1) * 32];
        float w2 = W[(size_t)(k + 2) * 32];
        float w3 = W[(size_t)(k + 3) * 32];
#pragma unroll
        for (int r = 0; r < 8; ++r) {
            float4 a = *reinterpret_cast<const float4*>(
                &hs[(wave * 8 + r) * 512 + k]);
            acc[r] += a.x * w0 + a.y * w1 + a.z * w2 + a.w * w3;
        }
    }
#pragma unroll
    for (int r = 0; r < 8; ++r) {
        int grow = n0 + wave * 8 + r;
        if (grow < N_NODES) xw2[(size_t)grow * 64 + j] = acc[r];
    }
}

// Fused edge+node layer 2 + log_softmax: one wave per node (4 nodes/block).
// Lane (ej, cg) owns 4 channels; no online rescale; prefetched.
__global__ __launch_bounds__(256) void k_node2f(const int* __restrict__ offs,
        const int* __restrict__ ssrc, const float* __restrict__ xw2,
        const float* __restrict__ att2, const float* __restrict__ b2,
        float* __restrict__ out) {
    constexpr int C = 8;
    __shared__ int slds[4 * MAXD2];
    int t = threadIdx.x;
    int wv = t >> 6;
    int n = blockIdx.x * 4 + wv;
    int lane = t & 63;
    int beg = offs[n], dcnt = offs[n + 1] - beg;
    int cap = (dcnt < MAXD2) ? dcnt : MAXD2;
    int* sl = slds + wv * MAXD2;
    for (int i = lane; i < cap; i += 64) sl[i] = ssrc[beg + i];
    __syncthreads();
    int ej = lane >> 3;                  // edge slot
    int cg = lane & 7;                   // channel group of 4
    float4 xr = *reinterpret_cast<const float4*>(xw2 + (size_t)n * 64 + 32 + cg * 4);
    float4 at = *reinterpret_cast<const float4*>(att2 + cg * 4);
    float l = 0.f;
    float4 ac = {0.f, 0.f, 0.f, 0.f};
    auto fetch = [&](int base, float4& xa) {
        int i1 = base + ej;
        int i1c = (i1 < dcnt) ? i1 : (dcnt - 1);
        int sj = (i1c < MAXD2) ? sl[i1c] : ssrc[beg + i1c];
        xa = *reinterpret_cast<const float4*>(xw2 + (size_t)sj * 64 + cg * 4);
    };
    float4 xa;
    fetch(0, xa);
    for (int base = 0; base < dcnt; base += C) {
        float4 na;
        fetch(base + C < dcnt ? base + C : base, na);
        float p = lrelu(xa.x + xr.x) * at.x + lrelu(xa.y + xr.y) * at.y
                + lrelu(xa.z + xr.z) * at.z + lrelu(xa.w + xr.w) * at.w;
        p += __shfl_xor(p, 1);
        p += __shfl_xor(p, 2);
        p += __shfl_xor(p, 4);
        if (base + ej >= dcnt) p = -1e30f;
        float w = __expf(fminf(p, 60.f));
        l += w;
        ac.x += w * xa.x; ac.y += w * xa.y;
        ac.z += w * xa.z; ac.w += w * xa.w;
        xa = na;
    }
#pragma unroll
    for (int o = 8; o < 64; o <<= 1) {
        l    += __shfl_xor(l, o);
        ac.x += __shfl_xor(ac.x, o); ac.y += __shfl_xor(ac.y, o);
        ac.z += __shfl_xor(ac.z, o); ac.w += __shfl_xor(ac.w, o);
    }
    float inv = 1.f / (l + 1e-16f);
    float4 bb = *reinterpret_cast<const float4*>(b2 + cg * 4);
    float4 v;
    v.x = ac.x * inv + bb.x; v.y = ac.y * inv + bb.y;
    v.z = ac.z * inv + bb.z; v.w = ac.w * inv + bb.w;
    // log_softmax over 32 channels: local max/sum over 4, then across cg
    float mx = fmaxf(fmaxf(v.x, v.y), fmaxf(v.z, v.w));
    mx = fmaxf(mx, __shfl_xor(mx, 1));
    mx = fmaxf(mx, __shfl_xor(mx, 2));
    mx = fmaxf(mx, __shfl_xor(mx, 4));
    float se = __expf(v.x - mx) + __expf(v.y - mx)
             + __expf(v.z - mx) + __expf(v.w - mx);
    se += __shfl_xor(se, 1);
    se += __shfl_xor(se, 2);
    se += __shfl_xor(se, 4);
    float ls = __logf(se);
    v.x = v.x - mx - ls; v.y = v.y - mx - ls;
    v.z = v.z - mx - ls; v.w = v.w - mx - ls;
    if (ej == 0)
        *reinterpret_cast<float4*>(out + (size_t)n * 32 + cg * 4) = v;
}

// ---------------- launch ----------------

extern "C" void kernel_launch(void* const* d_in, const int* in_sizes, int n_in,
                              void* d_out, int out_size, void* d_ws, size_t ws_size,
                              hipStream_t stream) {
    (void)in_sizes; (void)n_in; (void)out_size; (void)ws_size;
    const float* x    = (const float*)d_in[0];
    const int*   ei   = (const int*)d_in[1];
    const float* W1l  = (const float*)d_in[2];
    const float* W1r  = (const float*)d_in[3];
    const float* att1 = (const float*)d_in[4];
    const float* b1   = (const float*)d_in[5];
    const float* W2l  = (const float*)d_in[6];
    const float* W2r  = (const float*)d_in[7];
    const float* att2 = (const float*)d_in[8];
    const float* b2   = (const float*)d_in[9];
    float* outp = (float*)d_out;

    char* ws = (char*)d_ws;
    size_t o = 0;
    auto alloc = [&](size_t bytes) {
        char* p = ws + o;
        o = (o + bytes + 255) & ~(size_t)255;
        return p;
    };
    unsigned short* xl1b = (unsigned short*)alloc((size_t)N_NODES * 512 * 2);
    float* xr1    = (float*)alloc((size_t)N_NODES * 512 * 4);
    float* h1     = (float*)alloc((size_t)N_NODES * 512 * 4);
    float* xw2    = (float*)alloc((size_t)N_NODES * 64 * 4);
    unsigned short* Abf = (unsigned short*)alloc((size_t)N_NODES * 768 * 2);
    unsigned short* Bbf = (unsigned short*)alloc((size_t)1024 * 768 * 2);
    int*   deg    = (int*)alloc((size_t)N_NODES * 4);
    int*   cursor = (int*)alloc((size_t)N_NODES * 4);
    int*   offs   = (int*)alloc((size_t)(N_NODES + 1) * 4);
    int*   ssrc   = (int*)alloc((size_t)ET * 4);

    hipMemsetAsync(deg, 0, (size_t)N_NODES * 4, stream);
    hipMemsetAsync(cursor, 0, (size_t)N_NODES * 4, stream);

    k_count  <<<(ET + 255) / 256,      256, 0, stream>>>(ei, deg);
    k_scan   <<<1,                    1024, 0, stream>>>(deg, offs);
    k_scatter<<<(ET + 255) / 256,      256, 0, stream>>>(ei, offs, cursor, ssrc);
    k_conv_x <<<(N_NODES * 64 + 255) / 256, 256, 0, stream>>>(x, Abf);
    k_conv_w <<<(1024 * 64 + 255) / 256,    256, 0, stream>>>(W1l, W1r, Bbf);
    k_mfma1  <<<dim3(79, 8),           256, 0, stream>>>(Abf, Bbf, xl1b, xr1);
    k_node1f <<<N_NODES,               512, 0, stream>>>(offs, ssrc, xl1b, xr1, att1, b1, h1);
    k_gemm2  <<<(N_NODES + 31) / 32,   256, 0, stream>>>(h1, W2l, W2r, xw2);
    k_node2f <<<N_NODES / 4,           256, 0, stream>>>(offs, ssrc, xw2, att2, b2, outp);
}

// Round 12
// 294.684 us; speedup vs baseline: 1.3930x; 1.0217x over previous
//
#include <hip/hip_runtime.h>
#include <hip/hip_bf16.h>

// GATv2 x2 on MI355X — MFMA gemm1 (split-bf16), bf16 xl1 gather, DPP-reduced
// node kernels. R11 evidence: k_node1f is issue/latency-bound (FETCH halved,
// dur flat). The per-chunk serial chain ran through 3 ds_swizzle shuffles;
// replaced with VALU DPP adds (quad_perm 0xB1 / 0x4E + row_half_mirror 0x141
// — any half-pairing works for a sum once quads hold quad-sums). Alpha fma
// reduce tree-split into two independent 4-chains; LDS ssrc cache stores
// BYTE OFFSETS (sj<<10 / sj<<8) to delete per-fetch address VALU.

constexpr int N_NODES = 10000;
constexpr int N_EDGES = 320000;
constexpr int ET      = N_EDGES + N_NODES;   // 330000 incl. self loops
constexpr float NEG_SLOPE = 0.2f;
constexpr int MAXD1 = 384;                   // LDS ssrc cache (layer1)
constexpr int MAXD2 = 160;                   // per node (layer2, 4 nodes/block)

typedef __attribute__((ext_vector_type(8))) short short8;
typedef __attribute__((ext_vector_type(8))) unsigned short ushort8_t;
typedef __attribute__((ext_vector_type(4))) float floatx4;

__device__ __forceinline__ float lrelu(float a) {
    return fmaxf(a, NEG_SLOPE * a);          // 0.2a > a iff a < 0
}
__device__ __forceinline__ unsigned short f2bf(float f) {   // RNE
    unsigned u = __float_as_uint(f);
    unsigned r = u + 0x7FFFu + ((u >> 16) & 1u);
    return (unsigned short)(r >> 16);
}
__device__ __forceinline__ float bf2f(unsigned short h) {
    return __uint_as_float((unsigned)h << 16);
}
// sum over each aligned group of 8 lanes, result in all 8 (pure VALU, no LDS)
__device__ __forceinline__ float red8_dpp(float p) {
    int x;
    x = __builtin_amdgcn_update_dpp(0, __float_as_int(p), 0xB1, 0xF, 0xF, true);
    p += __int_as_float(x);                  // quad_perm [1,0,3,2] : xor 1
    x = __builtin_amdgcn_update_dpp(0, __float_as_int(p), 0x4E, 0xF, 0xF, true);
    p += __int_as_float(x);                  // quad_perm [2,3,0,1] : xor 2
    x = __builtin_amdgcn_update_dpp(0, __float_as_int(p), 0x141, 0xF, 0xF, true);
    p += __int_as_float(x);                  // row_half_mirror : cross-quad pair
    return p;
}

// ---------------- CSR build ----------------

__global__ void k_count(const int* __restrict__ ei, int* __restrict__ deg) {
    int e = blockIdx.x * 256 + threadIdx.x;
    if (e >= ET) return;
    int d = (e < N_EDGES) ? ei[N_EDGES + e] : (e - N_EDGES);
    atomicAdd(&deg[d], 1);
}

__global__ __launch_bounds__(1024) void k_scan(const int* __restrict__ deg,
                                               int* __restrict__ offs) {
    __shared__ int part[1024];
    const int CH = 10;                       // ceil(10000/1024)
    int t = threadIdx.x;
    int base = t * CH;
    int loc[CH];
    int s = 0;
    for (int i = 0; i < CH; ++i) {
        int idx = base + i;
        int v = (idx < N_NODES) ? deg[idx] : 0;
        loc[i] = s; s += v;
    }
    part[t] = s;
    __syncthreads();
    for (int o = 1; o < 1024; o <<= 1) {
        int add = (t >= o) ? part[t - o] : 0;
        __syncthreads();
        part[t] += add;
        __syncthreads();
    }
    int excl = part[t] - s;
    for (int i = 0; i < CH; ++i) {
        int idx = base + i;
        if (idx < N_NODES) offs[idx] = excl + loc[i];
    }
    if (t == 1023) offs[N_NODES] = part[1023];
}

__global__ void k_scatter(const int* __restrict__ ei, const int* __restrict__ offs,
                          int* __restrict__ cursor, int* __restrict__ ssrc) {
    int e = blockIdx.x * 256 + threadIdx.x;
    if (e >= ET) return;
    int s, d;
    if (e < N_EDGES) { s = ei[e]; d = ei[N_EDGES + e]; }
    else             { s = d = e - N_EDGES; }
    int pos = offs[d] + atomicAdd(&cursor[d], 1);
    ssrc[pos] = s;
}

// ---------------- layer 1: split-bf16 conversion + MFMA GEMM ----------------

// x[10000,256] fp32 -> A'[10000,768] bf16: segs [hi | lo | hi]
__global__ __launch_bounds__(256) void k_conv_x(const float* __restrict__ x,
        unsigned short* __restrict__ A) {
    int idx = blockIdx.x * 256 + threadIdx.x;       // N_NODES*64 threads
    if (idx >= N_NODES * 64) return;
    int m = idx >> 6, kg = (idx & 63) << 2;
    float4 v = *reinterpret_cast<const float4*>(x + (size_t)m * 256 + kg);
    ushort4 hi = make_ushort4(f2bf(v.x), f2bf(v.y), f2bf(v.z), f2bf(v.w));
    ushort4 lo = make_ushort4(f2bf(v.x - bf2f(hi.x)), f2bf(v.y - bf2f(hi.y)),
                              f2bf(v.z - bf2f(hi.z)), f2bf(v.w - bf2f(hi.w)));
    size_t base = (size_t)m * 768 + kg;
    *reinterpret_cast<ushort4*>(A + base)       = hi;
    *reinterpret_cast<ushort4*>(A + base + 256) = lo;
    *reinterpret_cast<ushort4*>(A + base + 512) = hi;
}

// W1l/W1r [256,512] fp32 -> Bt[1024,768] bf16 (transposed): segs [hi | hi | lo]
__global__ __launch_bounds__(256) void k_conv_w(const float* __restrict__ Wl,
        const float* __restrict__ Wr, unsigned short* __restrict__ Bt) {
    int idx = blockIdx.x * 256 + threadIdx.x;       // 1024*64 threads
    if (idx >= 1024 * 64) return;
    int n = idx >> 6, kg = (idx & 63) << 2;
    const float* src = (n < 512) ? (Wl + n) : (Wr + (n - 512));
    float v0 = src[(size_t)(kg + 0) * 512];
    float v1 = src[(size_t)(kg + 1) * 512];
    float v2 = src[(size_t)(kg + 2) * 512];
    float v3 = src[(size_t)(kg + 3) * 512];
    ushort4 hi = make_ushort4(f2bf(v0), f2bf(v1), f2bf(v2), f2bf(v3));
    ushort4 lo = make_ushort4(f2bf(v0 - bf2f(hi.x)), f2bf(v1 - bf2f(hi.y)),
                              f2bf(v2 - bf2f(hi.z)), f2bf(v3 - bf2f(hi.w)));
    size_t base = (size_t)n * 768 + kg;
    *reinterpret_cast<ushort4*>(Bt + base)       = hi;
    *reinterpret_cast<ushort4*>(Bt + base + 256) = hi;
    *reinterpret_cast<ushort4*>(Bt + base + 512) = lo;
}

// 128x128 tile MFMA GEMM, M=10000 N=1024 K=768, grid (79,8), 4 waves/block.
// Columns <512 (xl) stored as bf16; columns >=512 (xr) stored fp32.
__global__ __launch_bounds__(256) void k_mfma1(const unsigned short* __restrict__ A,
        const unsigned short* __restrict__ Bt, unsigned short* __restrict__ xl1b,
        float* __restrict__ xr1) {
    __shared__ unsigned short As[128 * 40];   // stride 40 (80B): 2-way max = free
    __shared__ unsigned short Bs[128 * 40];
    int t = threadIdx.x;
    int wave = t >> 6, L = t & 63;
    int wm = wave & 1, wn = wave >> 1;
    int row0 = blockIdx.x * 128, n0 = blockIdx.y * 128;
    int q = L >> 4, rr = L & 15;
    floatx4 acc[4][4];
#pragma unroll
    for (int i = 0; i < 4; ++i)
#pragma unroll
        for (int j = 0; j < 4; ++j) acc[i][j] = (floatx4){0.f, 0.f, 0.f, 0.f};
    int ra = t >> 2,        ka = (t & 3) * 8;
    int rb = (t + 256) >> 2, kb = ((t + 256) & 3) * 8;
    int gma = row0 + ra; gma = (gma < N_NODES) ? gma : (N_NODES - 1);
    int gmb = row0 + rb; gmb = (gmb < N_NODES) ? gmb : (N_NODES - 1);
    for (int kc = 0; kc < 768; kc += 32) {
        __syncthreads();
        *reinterpret_cast<uint4*>(&As[ra * 40 + ka]) =
            *reinterpret_cast<const uint4*>(A + (size_t)gma * 768 + kc + ka);
        *reinterpret_cast<uint4*>(&As[rb * 40 + kb]) =
            *reinterpret_cast<const uint4*>(A + (size_t)gmb * 768 + kc + kb);
        *reinterpret_cast<uint4*>(&Bs[ra * 40 + ka]) =
            *reinterpret_cast<const uint4*>(Bt + (size_t)(n0 + ra) * 768 + kc + ka);
        *reinterpret_cast<uint4*>(&Bs[rb * 40 + kb]) =
            *reinterpret_cast<const uint4*>(Bt + (size_t)(n0 + rb) * 768 + kc + kb);
        __syncthreads();
        short8 af[4], bf[4];
#pragma unroll
        for (int st = 0; st < 4; ++st)
            af[st] = *reinterpret_cast<const short8*>(
                &As[(wm * 64 + st * 16 + rr) * 40 + q * 8]);
#pragma unroll
        for (int st = 0; st < 4; ++st)
            bf[st] = *reinterpret_cast<const short8*>(
                &Bs[(wn * 64 + st * 16 + rr) * 40 + q * 8]);
#pragma unroll
        for (int i = 0; i < 4; ++i)
#pragma unroll
            for (int j = 0; j < 4; ++j)
                acc[i][j] = __builtin_amdgcn_mfma_f32_16x16x32_bf16(
                    af[i], bf[j], acc[i][j], 0, 0, 0);
    }
    // epilogue: C/D layout col=lane&15, row=(lane>>4)*4+reg  [m89/m91]
#pragma unroll
    for (int j = 0; j < 4; ++j) {
        int gc = n0 + wn * 64 + j * 16 + rr;
        if (gc < 512) {
#pragma unroll
            for (int i = 0; i < 4; ++i)
#pragma unroll
                for (int r = 0; r < 4; ++r) {
                    int gr = row0 + wm * 64 + i * 16 + q * 4 + r;
                    if (gr < N_NODES)
                        xl1b[(size_t)gr * 512 + gc] = f2bf(acc[i][j][r]);
                }
        } else {
            int col = gc - 512;
#pragma unroll
            for (int i = 0; i < 4; ++i)
#pragma unroll
                for (int r = 0; r < 4; ++r) {
                    int gr = row0 + wm * 64 + i * 16 + q * 4 + r;
                    if (gr < N_NODES)
                        xr1[(size_t)gr * 512 + col] = acc[i][j][r];
                }
        }
    }
}

// Fused edge+node layer 1: one block (512 thr = 8 waves) per node; wave = head.
// Lane (ej,cg): bf16 row gather, per-slot accumulation, DPP 8-lane reduce.
__global__ __launch_bounds__(512) void k_node1f(const int* __restrict__ offs,
        const int* __restrict__ ssrc, const unsigned short* __restrict__ xl1b,
        const float* __restrict__ xr1, const float* __restrict__ att1,
        const float* __restrict__ b1, float* __restrict__ h1) {
    constexpr int C = 8;                 // edges per chunk
    __shared__ int slds[MAXD1];          // BYTE offsets (sj * 1024)
    int n = blockIdx.x;
    int t = threadIdx.x;                 // t = h*64 + lane
    int h = t >> 6, lane = t & 63;
    int beg = offs[n], dcnt = offs[n + 1] - beg;
    int cap = (dcnt < MAXD1) ? dcnt : MAXD1;
    for (int i = t; i < cap; i += 512) slds[i] = ssrc[beg + i] << 10;
    __syncthreads();
    int ej = lane >> 3;                  // edge slot within chunk
    int cg = lane & 7;                   // channel group of 8
    float xrv[8], atv[8];
    {
        const float* xrrow = xr1 + (size_t)n * 512 + h * 64 + cg * 8;
        const float* atrow = att1 + h * 64 + cg * 8;
#pragma unroll
        for (int i = 0; i < 8; ++i) { xrv[i] = xrrow[i]; atv[i] = atrow[i]; }
    }
    float l = 0.f;
    float acc8[8];
#pragma unroll
    for (int i = 0; i < 8; ++i) acc8[i] = 0.f;

    const char* xlbase = reinterpret_cast<const char*>(xl1b) + h * 128 + cg * 16;
    auto fetch = [&](int base, ushort8_t& u) {
        int i1 = base + ej;
        int i1c = (i1 < dcnt) ? i1 : (dcnt - 1);       // dup row; w=0 masks
        int off = (i1c < MAXD1) ? slds[i1c] : (ssrc[beg + i1c] << 10);
        u = *reinterpret_cast<const ushort8_t*>(xlbase + off);
    };
    ushort8_t ux;
    fetch(0, ux);
    for (int base = 0; base < dcnt; base += C) {
        ushort8_t un;
        fetch(base + C < dcnt ? base + C : base, un);  // dbuf prefetch
        float xs[8];
#pragma unroll
        for (int i = 0; i < 8; ++i) xs[i] = bf2f(ux[i]);
        // two independent 4-deep fma chains, merged once
        float p0 = 0.f, p1 = 0.f;
#pragma unroll
        for (int i = 0; i < 4; ++i) {
            p0 += lrelu(xs[i] + xrv[i]) * atv[i];
            p1 += lrelu(xs[i + 4] + xrv[i + 4]) * atv[i + 4];
        }
        float p = red8_dpp(p0 + p1);     // own edge's alpha in all 8 cg lanes
        if (base + ej >= dcnt) p = -1e30f;
        float w = __expf(fminf(p, 60.f));    // exp(-1e30) = 0
        l += w;
#pragma unroll
        for (int i = 0; i < 8; ++i) acc8[i] += w * xs[i];
        ux = un;
    }
    // reduce over the 8 edge slots (once per node)
#pragma unroll
    for (int o = 8; o < 64; o <<= 1) {
        l += __shfl_xor(l, o);
#pragma unroll
        for (int i = 0; i < 8; ++i) acc8[i] += __shfl_xor(acc8[i], o);
    }
    float inv = 1.f / (l + 1e-16f);
    float v8[8];
    {
        const float* brow = b1 + h * 64 + cg * 8;
#pragma unroll
        for (int i = 0; i < 8; ++i) {
            float v = acc8[i] * inv + brow[i];
            v8[i] = (v > 0.f) ? v : expm1f(v);   // elu
        }
    }
    if (ej == 0) {
        float4 va = {v8[0], v8[1], v8[2], v8[3]};
        float4 vb = {v8[4], v8[5], v8[6], v8[7]};
        float* dst = h1 + (size_t)n * 512 + h * 64 + cg * 8;
        *reinterpret_cast<float4*>(dst)     = va;
        *reinterpret_cast<float4*>(dst + 4) = vb;
    }
}

// ---------------- layer 2 ----------------

// 32 rows x 64 cols per block, 256 thr = 4 waves; wave owns 8 rows.
// Lane j reads W column j (coalesced across lanes); h1 rows in LDS broadcast.
__global__ __launch_bounds__(256) void k_gemm2(const float* __restrict__ h1,
        const float* __restrict__ Wl, const float* __restrict__ Wr,
        float* __restrict__ xw2) {
    __shared__ float hs[32 * 512];       // 64 KB
    int t = threadIdx.x;
    int wave = t >> 6, j = t & 63;
    int n0 = blockIdx.x * 32;
    {
        float4* hdst = reinterpret_cast<float4*>(hs);
        for (int i = t; i < 32 * 128; i += 256) {
            int rrow = i >> 7;
            int grow = n0 + rrow;
            grow = (grow < N_NODES) ? grow : (N_NODES - 1);
            hdst[i] = reinterpret_cast<const float4*>(
                          h1 + (size_t)grow * 512)[i & 127];
        }
    }
    __syncthreads();
    const float* W = (j < 32) ? (Wl + j) : (Wr + (j - 32));
    float acc[8];
#pragma unroll
    for (int r = 0; r < 8; ++r) acc[r] = 0.f;
    for (int k = 0; k < 512; k += 4) {
        float w0 = W[(size_t)(k + 0) * 32];
        float w1 = W[(size_t)(k + 1) * 32];
        float w2 = W[(size_t)(k + 2) * 32];
        float w3 = W[(size_t)(k + 3) * 32];
#pragma unroll
        for (int r = 0; r < 8; ++r) {
            float4 a = *reinterpret_cast<const float4*>(
                &hs[(wave * 8 + r) * 512 + k]);
            acc[r] += a.x * w0 + a.y * w1 + a.z * w2 + a.w * w3;
        }
    }
#pragma unroll
    for (int r = 0; r < 8; ++r) {
        int grow = n0 + wave * 8 + r;
        if (grow < N_NODES) xw2[(size_t)grow * 64 + j] = acc[r];
    }
}

// Fused edge+node layer 2 + log_softmax: one wave per node (4 nodes/block).
// Lane (ej, cg) owns 4 channels; DPP reduce; byte-offset ssrc cache.
__global__ __launch_bounds__(256) void k_node2f(const int* __restrict__ offs,
        const int* __restrict__ ssrc, const float* __restrict__ xw2,
        const float* __restrict__ att2, const float* __restrict__ b2,
        float* __restrict__ out) {
    constexpr int C = 8;
    __shared__ int slds[4 * MAXD2];      // BYTE offsets (sj * 256)
    int t = threadIdx.x;
    int wv = t >> 6;
    int n = blockIdx.x * 4 + wv;
    int lane = t & 63;
    int beg = offs[n], dcnt = offs[n + 1] - beg;
    int cap = (dcnt < MAXD2) ? dcnt : MAXD2;
    int* sl = slds + wv * MAXD2;
    for (int i = lane; i < cap; i += 64) sl[i] = ssrc[beg + i] << 8;
    __syncthreads();
    int ej = lane >> 3;                  // edge slot
    int cg = lane & 7;                   // channel group of 4
    float4 xr = *reinterpret_cast<const float4*>(xw2 + (size_t)n * 64 + 32 + cg * 4);
    float4 at = *reinterpret_cast<const float4*>(att2 + cg * 4);
    float l = 0.f;
    float4 ac = {0.f, 0.f, 0.f, 0.f};
    const char* xwbase = reinterpret_cast<const char*>(xw2) + cg * 16;
    auto fetch = [&](int base, float4& xa) {
        int i1 = base + ej;
        int i1c = (i1 < dcnt) ? i1 : (dcnt - 1);
        int off = (i1c < MAXD2) ? sl[i1c] : (ssrc[beg + i1c] << 8);
        xa = *reinterpret_cast<const float4*>(xwbase + off);
    };
    float4 xa;
    fetch(0, xa);
    for (int base = 0; base < dcnt; base += C) {
        float4 na;
        fetch(base + C < dcnt ? base + C : base, na);
        float p0 = lrelu(xa.x + xr.x) * at.x + lrelu(xa.z + xr.z) * at.z;
        float p1 = lrelu(xa.y + xr.y) * at.y + lrelu(xa.w + xr.w) * at.w;
        float p = red8_dpp(p0 + p1);
        if (base + ej >= dcnt) p = -1e30f;
        float w = __expf(fminf(p, 60.f));
        l += w;
        ac.x += w * xa.x; ac.y += w * xa.y;
        ac.z += w * xa.z; ac.w += w * xa.w;
        xa = na;
    }
#pragma unroll
    for (int o = 8; o < 64; o <<= 1) {
        l    += __shfl_xor(l, o);
        ac.x += __shfl_xor(ac.x, o); ac.y += __shfl_xor(ac.y, o);
        ac.z += __shfl_xor(ac.z, o); ac.w += __shfl_xor(ac.w, o);
    }
    float inv = 1.f / (l + 1e-16f);
    float4 bb = *reinterpret_cast<const float4*>(b2 + cg * 4);
    float4 v;
    v.x = ac.x * inv + bb.x; v.y = ac.y * inv + bb.y;
    v.z = ac.z * inv + bb.z; v.w = ac.w * inv + bb.w;
    // log_softmax over 32 channels: local max/sum over 4, then across cg
    float mx = fmaxf(fmaxf(v.x, v.y), fmaxf(v.z, v.w));
    mx = fmaxf(mx, __shfl_xor(mx, 1));
    mx = fmaxf(mx, __shfl_xor(mx, 2));
    mx = fmaxf(mx, __shfl_xor(mx, 4));
    float se = __expf(v.x - mx) + __expf(v.y - mx)
             + __expf(v.z - mx) + __expf(v.w - mx);
    se += __shfl_xor(se, 1);
    se += __shfl_xor(se, 2);
    se += __shfl_xor(se, 4);
    float ls = __logf(se);
    v.x = v.x - mx - ls; v.y = v.y - mx - ls;
    v.z = v.z - mx - ls; v.w = v.w - mx - ls;
    if (ej == 0)
        *reinterpret_cast<float4*>(out + (size_t)n * 32 + cg * 4) = v;
}

// ---------------- launch ----------------

extern "C" void kernel_launch(void* const* d_in, const int* in_sizes, int n_in,
                              void* d_out, int out_size, void* d_ws, size_t ws_size,
                              hipStream_t stream) {
    (void)in_sizes; (void)n_in; (void)out_size; (void)ws_size;
    const float* x    = (const float*)d_in[0];
    const int*   ei   = (const int*)d_in[1];
    const float* W1l  = (const float*)d_in[2];
    const float* W1r  = (const float*)d_in[3];
    const float* att1 = (const float*)d_in[4];
    const float* b1   = (const float*)d_in[5];
    const float* W2l  = (const float*)d_in[6];
    const float* W2r  = (const float*)d_in[7];
    const float* att2 = (const float*)d_in[8];
    const float* b2   = (const float*)d_in[9];
    float* outp = (float*)d_out;

    char* ws = (char*)d_ws;
    size_t o = 0;
    auto alloc = [&](size_t bytes) {
        char* p = ws + o;
        o = (o + bytes + 255) & ~(size_t)255;
        return p;
    };
    unsigned short* xl1b = (unsigned short*)alloc((size_t)N_NODES * 512 * 2);
    float* xr1    = (float*)alloc((size_t)N_NODES * 512 * 4);
    float* h1     = (float*)alloc((size_t)N_NODES * 512 * 4);
    float* xw2    = (float*)alloc((size_t)N_NODES * 64 * 4);
    unsigned short* Abf = (unsigned short*)alloc((size_t)N_NODES * 768 * 2);
    unsigned short* Bbf = (unsigned short*)alloc((size_t)1024 * 768 * 2);
    int*   deg    = (int*)alloc((size_t)N_NODES * 4);
    int*   cursor = (int*)alloc((size_t)N_NODES * 4);
    int*   offs   = (int*)alloc((size_t)(N_NODES + 1) * 4);
    int*   ssrc   = (int*)alloc((size_t)ET * 4);

    hipMemsetAsync(deg, 0, (size_t)N_NODES * 4, stream);
    hipMemsetAsync(cursor, 0, (size_t)N_NODES * 4, stream);

    k_count  <<<(ET + 255) / 256,      256, 0, stream>>>(ei, deg);
    k_scan   <<<1,                    1024, 0, stream>>>(deg, offs);
    k_scatter<<<(ET + 255) / 256,      256, 0, stream>>>(ei, offs, cursor, ssrc);
    k_conv_x <<<(N_NODES * 64 + 255) / 256, 256, 0, stream>>>(x, Abf);
    k_conv_w <<<(1024 * 64 + 255) / 256,    256, 0, stream>>>(W1l, W1r, Bbf);
    k_mfma1  <<<dim3(79, 8),           256, 0, stream>>>(Abf, Bbf, xl1b, xr1);
    k_node1f <<<N_NODES,               512, 0, stream>>>(offs, ssrc, xl1b, xr1, att1, b1, h1);
    k_gemm2  <<<(N_NODES + 31) / 32,   256, 0, stream>>>(h1, W2l, W2r, xw2);
    k_node2f <<<N_NODES / 4,           256, 0, stream>>>(offs, ssrc, xw2, att2, b2, outp);
}

// Round 13
// 290.666 us; speedup vs baseline: 1.4122x; 1.0138x over previous
//
#include <hip/hip_runtime.h>
#include <hip/hip_bf16.h>

// GATv2 x2 on MI355X — MFMA gemm1 (split-bf16), bf16 xl1 gather, DPP reduce,
// deep software pipeline in node kernels (offsets +3 chunks, rows +2 chunks:
// covers the ds_read ~120cyc + gather ~200-900cyc chain that prefetch-1
// couldn't). Branchless fast loop (max degree ~60 << MAXD1; slow path kept
// for correctness, never taken). Launches 12 -> 8: k_prep fuses count+convs;
// deg doubles as scatter countdown cursor (no cursor buf / memset).

constexpr int N_NODES = 10000;
constexpr int N_EDGES = 320000;
constexpr int ET      = N_EDGES + N_NODES;   // 330000 incl. self loops
constexpr float NEG_SLOPE = 0.2f;
constexpr int MAXD1 = 384;                   // LDS ssrc cache (layer1)
constexpr int MAXD2 = 384;                   // (layer2, 4 nodes/block)

constexpr int NB_COUNT = (ET + 255) / 256;          // 1290
constexpr int NB_CONVX = (N_NODES * 64) / 256;      // 2500
constexpr int NB_CONVW = (1024 * 64) / 256;         // 256

typedef __attribute__((ext_vector_type(8))) short short8;
typedef __attribute__((ext_vector_type(8))) unsigned short ushort8_t;
typedef __attribute__((ext_vector_type(4))) float floatx4;

__device__ __forceinline__ float lrelu(float a) {
    return fmaxf(a, NEG_SLOPE * a);
}
__device__ __forceinline__ unsigned short f2bf(float f) {   // RNE
    unsigned u = __float_as_uint(f);
    unsigned r = u + 0x7FFFu + ((u >> 16) & 1u);
    return (unsigned short)(r >> 16);
}
__device__ __forceinline__ float bf2f(unsigned short h) {
    return __uint_as_float((unsigned)h << 16);
}
// sum over each aligned group of 8 lanes, result in all 8 (pure VALU)
__device__ __forceinline__ float red8_dpp(float p) {
    int x;
    x = __builtin_amdgcn_update_dpp(0, __float_as_int(p), 0xB1, 0xF, 0xF, true);
    p += __int_as_float(x);                  // quad_perm [1,0,3,2]
    x = __builtin_amdgcn_update_dpp(0, __float_as_int(p), 0x4E, 0xF, 0xF, true);
    p += __int_as_float(x);                  // quad_perm [2,3,0,1]
    x = __builtin_amdgcn_update_dpp(0, __float_as_int(p), 0x141, 0xF, 0xF, true);
    p += __int_as_float(x);                  // row_half_mirror
    return p;
}

// ---------------- fused prep: deg count + conv_x + conv_w ----------------

__global__ __launch_bounds__(256) void k_prep(const int* __restrict__ ei,
        int* __restrict__ deg, const float* __restrict__ x,
        unsigned short* __restrict__ A, const float* __restrict__ Wl,
        const float* __restrict__ Wr, unsigned short* __restrict__ Bt) {
    int b = blockIdx.x, t = threadIdx.x;
    if (b < NB_COUNT) {
        int e = b * 256 + t;
        if (e >= ET) return;
        int d = (e < N_EDGES) ? ei[N_EDGES + e] : (e - N_EDGES);
        atomicAdd(&deg[d], 1);
    } else if (b < NB_COUNT + NB_CONVX) {
        int idx = (b - NB_COUNT) * 256 + t;       // < N_NODES*64
        int m = idx >> 6, kg = (idx & 63) << 2;
        float4 v = *reinterpret_cast<const float4*>(x + (size_t)m * 256 + kg);
        ushort4 hi = make_ushort4(f2bf(v.x), f2bf(v.y), f2bf(v.z), f2bf(v.w));
        ushort4 lo = make_ushort4(f2bf(v.x - bf2f(hi.x)), f2bf(v.y - bf2f(hi.y)),
                                  f2bf(v.z - bf2f(hi.z)), f2bf(v.w - bf2f(hi.w)));
        size_t base = (size_t)m * 768 + kg;
        *reinterpret_cast<ushort4*>(A + base)       = hi;
        *reinterpret_cast<ushort4*>(A + base + 256) = lo;
        *reinterpret_cast<ushort4*>(A + base + 512) = hi;
    } else {
        int idx = (b - NB_COUNT - NB_CONVX) * 256 + t;   // < 1024*64
        int n = idx >> 6, kg = (idx & 63) << 2;
        const float* src = (n < 512) ? (Wl + n) : (Wr + (n - 512));
        float v0 = src[(size_t)(kg + 0) * 512];
        float v1 = src[(size_t)(kg + 1) * 512];
        float v2 = src[(size_t)(kg + 2) * 512];
        float v3 = src[(size_t)(kg + 3) * 512];
        ushort4 hi = make_ushort4(f2bf(v0), f2bf(v1), f2bf(v2), f2bf(v3));
        ushort4 lo = make_ushort4(f2bf(v0 - bf2f(hi.x)), f2bf(v1 - bf2f(hi.y)),
                                  f2bf(v2 - bf2f(hi.z)), f2bf(v3 - bf2f(hi.w)));
        size_t base = (size_t)n * 768 + kg;
        *reinterpret_cast<ushort4*>(Bt + base)       = hi;
        *reinterpret_cast<ushort4*>(Bt + base + 256) = hi;
        *reinterpret_cast<ushort4*>(Bt + base + 512) = lo;
    }
}

// ---------------- CSR scan + scatter ----------------

__global__ __launch_bounds__(1024) void k_scan(const int* __restrict__ deg,
                                               int* __restrict__ offs) {
    __shared__ int part[1024];
    const int CH = 10;                       // ceil(10000/1024)
    int t = threadIdx.x;
    int base = t * CH;
    int loc[CH];
    int s = 0;
    for (int i = 0; i < CH; ++i) {
        int idx = base + i;
        int v = (idx < N_NODES) ? deg[idx] : 0;
        loc[i] = s; s += v;
    }
    part[t] = s;
    __syncthreads();
    for (int o = 1; o < 1024; o <<= 1) {
        int add = (t >= o) ? part[t - o] : 0;
        __syncthreads();
        part[t] += add;
        __syncthreads();
    }
    int excl = part[t] - s;
    for (int i = 0; i < CH; ++i) {
        int idx = base + i;
        if (idx < N_NODES) offs[idx] = excl + loc[i];
    }
    if (t == 1023) offs[N_NODES] = part[1023];
}

// deg doubles as countdown cursor: pos = offs[d] + (--deg[d])
__global__ void k_scatter(const int* __restrict__ ei, const int* __restrict__ offs,
                          int* __restrict__ deg, int* __restrict__ ssrc) {
    int e = blockIdx.x * 256 + threadIdx.x;
    if (e >= ET) return;
    int s, d;
    if (e < N_EDGES) { s = ei[e]; d = ei[N_EDGES + e]; }
    else             { s = d = e - N_EDGES; }
    int pos = offs[d] + atomicAdd(&deg[d], -1) - 1;
    ssrc[pos] = s;
}

// ---------------- layer 1 MFMA GEMM ----------------

// 128x128 tile, M=10000 N=1024 K=768, grid (79,8), 4 waves/block.
// Columns <512 (xl) stored bf16; columns >=512 (xr) stored fp32.
__global__ __launch_bounds__(256) void k_mfma1(const unsigned short* __restrict__ A,
        const unsigned short* __restrict__ Bt, unsigned short* __restrict__ xl1b,
        float* __restrict__ xr1) {
    __shared__ unsigned short As[128 * 40];   // stride 40: 2-way max = free
    __shared__ unsigned short Bs[128 * 40];
    int t = threadIdx.x;
    int wave = t >> 6, L = t & 63;
    int wm = wave & 1, wn = wave >> 1;
    int row0 = blockIdx.x * 128, n0 = blockIdx.y * 128;
    int q = L >> 4, rr = L & 15;
    floatx4 acc[4][4];
#pragma unroll
    for (int i = 0; i < 4; ++i)
#pragma unroll
        for (int j = 0; j < 4; ++j) acc[i][j] = (floatx4){0.f, 0.f, 0.f, 0.f};
    int ra = t >> 2,        ka = (t & 3) * 8;
    int rb = (t + 256) >> 2, kb = ((t + 256) & 3) * 8;
    int gma = row0 + ra; gma = (gma < N_NODES) ? gma : (N_NODES - 1);
    int gmb = row0 + rb; gmb = (gmb < N_NODES) ? gmb : (N_NODES - 1);
    for (int kc = 0; kc < 768; kc += 32) {
        __syncthreads();
        *reinterpret_cast<uint4*>(&As[ra * 40 + ka]) =
            *reinterpret_cast<const uint4*>(A + (size_t)gma * 768 + kc + ka);
        *reinterpret_cast<uint4*>(&As[rb * 40 + kb]) =
            *reinterpret_cast<const uint4*>(A + (size_t)gmb * 768 + kc + kb);
        *reinterpret_cast<uint4*>(&Bs[ra * 40 + ka]) =
            *reinterpret_cast<const uint4*>(Bt + (size_t)(n0 + ra) * 768 + kc + ka);
        *reinterpret_cast<uint4*>(&Bs[rb * 40 + kb]) =
            *reinterpret_cast<const uint4*>(Bt + (size_t)(n0 + rb) * 768 + kc + kb);
        __syncthreads();
        short8 af[4], bf[4];
#pragma unroll
        for (int st = 0; st < 4; ++st)
            af[st] = *reinterpret_cast<const short8*>(
                &As[(wm * 64 + st * 16 + rr) * 40 + q * 8]);
#pragma unroll
        for (int st = 0; st < 4; ++st)
            bf[st] = *reinterpret_cast<const short8*>(
                &Bs[(wn * 64 + st * 16 + rr) * 40 + q * 8]);
#pragma unroll
        for (int i = 0; i < 4; ++i)
#pragma unroll
            for (int j = 0; j < 4; ++j)
                acc[i][j] = __builtin_amdgcn_mfma_f32_16x16x32_bf16(
                    af[i], bf[j], acc[i][j], 0, 0, 0);
    }
    // epilogue: C/D layout col=lane&15, row=(lane>>4)*4+reg  [m89/m91]
#pragma unroll
    for (int j = 0; j < 4; ++j) {
        int gc = n0 + wn * 64 + j * 16 + rr;
        if (gc < 512) {
#pragma unroll
            for (int i = 0; i < 4; ++i)
#pragma unroll
                for (int r = 0; r < 4; ++r) {
                    int gr = row0 + wm * 64 + i * 16 + q * 4 + r;
                    if (gr < N_NODES)
                        xl1b[(size_t)gr * 512 + gc] = f2bf(acc[i][j][r]);
                }
        } else {
            int col = gc - 512;
#pragma unroll
            for (int i = 0; i < 4; ++i)
#pragma unroll
                for (int r = 0; r < 4; ++r) {
                    int gr = row0 + wm * 64 + i * 16 + q * 4 + r;
                    if (gr < N_NODES)
                        xr1[(size_t)gr * 512 + col] = acc[i][j][r];
                }
        }
    }
}

// Fused edge+node layer 1: one block (512 thr = 8 waves) per node; wave = head.
// Deep pipeline: ld_off +3 chunks (LDS), ld_row +2 chunks (global).
__global__ __launch_bounds__(512) void k_node1f(const int* __restrict__ offs,
        const int* __restrict__ ssrc, const unsigned short* __restrict__ xl1b,
        const float* __restrict__ xr1, const float* __restrict__ att1,
        const float* __restrict__ b1, float* __restrict__ h1) {
    constexpr int C = 8;
    __shared__ int slds[MAXD1];          // BYTE offsets (sj * 1024)
    int n = blockIdx.x;
    int t = threadIdx.x;
    int h = t >> 6, lane = t & 63;
    int beg = offs[n], dcnt = offs[n + 1] - beg;
    int cap = (dcnt < MAXD1) ? dcnt : MAXD1;
    for (int i = t; i < cap; i += 512) slds[i] = ssrc[beg + i] << 10;
    __syncthreads();
    int ej = lane >> 3;                  // edge slot
    int cg = lane & 7;                   // channel group of 8
    float xrv[8], atv[8];
    {
        const float* xrrow = xr1 + (size_t)n * 512 + h * 64 + cg * 8;
        const float* atrow = att1 + h * 64 + cg * 8;
#pragma unroll
        for (int i = 0; i < 8; ++i) { xrv[i] = xrrow[i]; atv[i] = atrow[i]; }
    }
    float l = 0.f;
    float acc8[8];
#pragma unroll
    for (int i = 0; i < 8; ++i) acc8[i] = 0.f;
    const char* xlbase = reinterpret_cast<const char*>(xl1b) + h * 128 + cg * 16;

    if (dcnt <= MAXD1) {
        // ---- fast path (always taken: max degree ~60) ----
        auto ld_off = [&](int base) -> int {
            int i1 = base + ej;
            int i1c = (i1 < dcnt) ? i1 : (dcnt - 1);   // always valid
            return slds[i1c];
        };
        auto ld_row = [&](int off) -> ushort8_t {
            return *reinterpret_cast<const ushort8_t*>(xlbase + off);
        };
        int off2 = ld_off(0);
        ushort8_t u0 = ld_row(off2);
        off2 = ld_off(C);
        ushort8_t u1 = ld_row(off2);
        off2 = ld_off(2 * C);
        for (int base = 0; base < dcnt; base += C) {
            ushort8_t u2 = ld_row(off2);           // row +2 chunks
            int off3 = ld_off(base + 3 * C);       // offset +3 chunks
            float xs[8];
#pragma unroll
            for (int i = 0; i < 8; ++i) xs[i] = bf2f(u0[i]);
            float p0 = 0.f, p1 = 0.f;
#pragma unroll
            for (int i = 0; i < 4; ++i) {
                p0 += lrelu(xs[i] + xrv[i]) * atv[i];
                p1 += lrelu(xs[i + 4] + xrv[i + 4]) * atv[i + 4];
            }
            float p = red8_dpp(p0 + p1);
            if (base + ej >= dcnt) p = -1e30f;
            float w = __expf(fminf(p, 60.f));
            l += w;
#pragma unroll
            for (int i = 0; i < 8; ++i) acc8[i] += w * xs[i];
            u0 = u1; u1 = u2; off2 = off3;
        }
    } else {
        // ---- slow path (theoretical only) ----
        for (int base = 0; base < dcnt; base += C) {
            int i1 = base + ej;
            int i1c = (i1 < dcnt) ? i1 : (dcnt - 1);
            int off = (i1c < MAXD1) ? slds[i1c] : (ssrc[beg + i1c] << 10);
            ushort8_t u = *reinterpret_cast<const ushort8_t*>(xlbase + off);
            float xs[8];
#pragma unroll
            for (int i = 0; i < 8; ++i) xs[i] = bf2f(u[i]);
            float p0 = 0.f, p1 = 0.f;
#pragma unroll
            for (int i = 0; i < 4; ++i) {
                p0 += lrelu(xs[i] + xrv[i]) * atv[i];
                p1 += lrelu(xs[i + 4] + xrv[i + 4]) * atv[i + 4];
            }
            float p = red8_dpp(p0 + p1);
            if (base + ej >= dcnt) p = -1e30f;
            float w = __expf(fminf(p, 60.f));
            l += w;
#pragma unroll
            for (int i = 0; i < 8; ++i) acc8[i] += w * xs[i];
        }
    }
    // reduce over the 8 edge slots
#pragma unroll
    for (int o = 8; o < 64; o <<= 1) {
        l += __shfl_xor(l, o);
#pragma unroll
        for (int i = 0; i < 8; ++i) acc8[i] += __shfl_xor(acc8[i], o);
    }
    float inv = 1.f / (l + 1e-16f);
    float v8[8];
    {
        const float* brow = b1 + h * 64 + cg * 8;
#pragma unroll
        for (int i = 0; i < 8; ++i) {
            float v = acc8[i] * inv + brow[i];
            v8[i] = (v > 0.f) ? v : expm1f(v);   // elu
        }
    }
    if (ej == 0) {
        float4 va = {v8[0], v8[1], v8[2], v8[3]};
        float4 vb = {v8[4], v8[5], v8[6], v8[7]};
        float* dst = h1 + (size_t)n * 512 + h * 64 + cg * 8;
        *reinterpret_cast<float4*>(dst)     = va;
        *reinterpret_cast<float4*>(dst + 4) = vb;
    }
}

// ---------------- layer 2 ----------------

// 32 rows x 64 cols per block, 256 thr = 4 waves; wave owns 8 rows.
__global__ __launch_bounds__(256) void k_gemm2(const float* __restrict__ h1,
        const float* __restrict__ Wl, const float* __restrict__ Wr,
        float* __restrict__ xw2) {
    __shared__ float hs[32 * 512];       // 64 KB
    int t = threadIdx.x;
    int wave = t >> 6, j = t & 63;
    int n0 = blockIdx.x * 32;
    {
        float4* hdst = reinterpret_cast<float4*>(hs);
        for (int i = t; i < 32 * 128; i += 256) {
            int rrow = i >> 7;
            int grow = n0 + rrow;
            grow = (grow < N_NODES) ? grow : (N_NODES - 1);
            hdst[i] = reinterpret_cast<const float4*>(
                          h1 + (size_t)grow * 512)[i & 127];
        }
    }
    __syncthreads();
    const float* W = (j < 32) ? (Wl + j) : (Wr + (j - 32));
    float acc[8];
#pragma unroll
    for (int r = 0; r < 8; ++r) acc[r] = 0.f;
    for (int k = 0; k < 512; k += 4) {
        float w0 = W[(size_t)(k + 0) * 32];
        float w1 = W[(size_t)(k + 1) * 32];
        float w2 = W[(size_t)(k + 2) * 32];
        float w3 = W[(size_t)(k + 3) * 32];
#pragma unroll
        for (int r = 0; r < 8; ++r) {
            float4 a = *reinterpret_cast<const float4*>(
                &hs[(wave * 8 + r) * 512 + k]);
            acc[r] += a.x * w0 + a.y * w1 + a.z * w2 + a.w * w3;
        }
    }
#pragma unroll
    for (int r = 0; r < 8; ++r) {
        int grow = n0 + wave * 8 + r;
        if (grow < N_NODES) xw2[(size_t)grow * 64 + j] = acc[r];
    }
}

// Fused edge+node layer 2 + log_softmax: one wave per node (4 nodes/block).
// Same deep pipeline; lane (ej, cg) owns 4 channels.
__global__ __launch_bounds__(256) void k_node2f(const int* __restrict__ offs,
        const int* __restrict__ ssrc, const float* __restrict__ xw2,
        const float* __restrict__ att2, const float* __restrict__ b2,
        float* __restrict__ out) {
    constexpr int C = 8;
    __shared__ int slds[4 * MAXD2];      // BYTE offsets (sj * 256)
    int t = threadIdx.x;
    int wv = t >> 6;
    int n = blockIdx.x * 4 + wv;
    int lane = t & 63;
    int beg = offs[n], dcnt = offs[n + 1] - beg;
    int cap = (dcnt < MAXD2) ? dcnt : MAXD2;
    int* sl = slds + wv * MAXD2;
    for (int i = lane; i < cap; i += 64) sl[i] = ssrc[beg + i] << 8;
    __syncthreads();
    int ej = lane >> 3;
    int cg = lane & 7;
    float4 xr = *reinterpret_cast<const float4*>(xw2 + (size_t)n * 64 + 32 + cg * 4);
    float4 at = *reinterpret_cast<const float4*>(att2 + cg * 4);
    float l = 0.f;
    float4 ac = {0.f, 0.f, 0.f, 0.f};
    const char* xwbase = reinterpret_cast<const char*>(xw2) + cg * 16;

    if (dcnt <= MAXD2) {
        auto ld_off = [&](int base) -> int {
            int i1 = base + ej;
            int i1c = (i1 < dcnt) ? i1 : (dcnt - 1);
            return sl[i1c];
        };
        auto ld_row = [&](int off) -> float4 {
            return *reinterpret_cast<const float4*>(xwbase + off);
        };
        int off2 = ld_off(0);
        float4 u0 = ld_row(off2);
        off2 = ld_off(C);
        float4 u1 = ld_row(off2);
        off2 = ld_off(2 * C);
        for (int base = 0; base < dcnt; base += C) {
            float4 u2 = ld_row(off2);
            int off3 = ld_off(base + 3 * C);
            float p0 = lrelu(u0.x + xr.x) * at.x + lrelu(u0.z + xr.z) * at.z;
            float p1 = lrelu(u0.y + xr.y) * at.y + lrelu(u0.w + xr.w) * at.w;
            float p = red8_dpp(p0 + p1);
            if (base + ej >= dcnt) p = -1e30f;
            float w = __expf(fminf(p, 60.f));
            l += w;
            ac.x += w * u0.x; ac.y += w * u0.y;
            ac.z += w * u0.z; ac.w += w * u0.w;
            u0 = u1; u1 = u2; off2 = off3;
        }
    } else {
        for (int base = 0; base < dcnt; base += C) {
            int i1 = base + ej;
            int i1c = (i1 < dcnt) ? i1 : (dcnt - 1);
            int off = (i1c < MAXD2) ? sl[i1c] : (ssrc[beg + i1c] << 8);
            float4 u0 = *reinterpret_cast<const float4*>(xwbase + off);
            float p0 = lrelu(u0.x + xr.x) * at.x + lrelu(u0.z + xr.z) * at.z;
            float p1 = lrelu(u0.y + xr.y) * at.y + lrelu(u0.w + xr.w) * at.w;
            float p = red8_dpp(p0 + p1);
            if (base + ej >= dcnt) p = -1e30f;
            float w = __expf(fminf(p, 60.f));
            l += w;
            ac.x += w * u0.x; ac.y += w * u0.y;
            ac.z += w * u0.z; ac.w += w * u0.w;
        }
    }
#pragma unroll
    for (int o = 8; o < 64; o <<= 1) {
        l    += __shfl_xor(l, o);
        ac.x += __shfl_xor(ac.x, o); ac.y += __shfl_xor(ac.y, o);
        ac.z += __shfl_xor(ac.z, o); ac.w += __shfl_xor(ac.w, o);
    }
    float inv = 1.f / (l + 1e-16f);
    float4 bb = *reinterpret_cast<const float4*>(b2 + cg * 4);
    float4 v;
    v.x = ac.x * inv + bb.x; v.y = ac.y * inv + bb.y;
    v.z = ac.z * inv + bb.z; v.w = ac.w * inv + bb.w;
    float mx = fmaxf(fmaxf(v.x, v.y), fmaxf(v.z, v.w));
    mx = fmaxf(mx, __shfl_xor(mx, 1));
    mx = fmaxf(mx, __shfl_xor(mx, 2));
    mx = fmaxf(mx, __shfl_xor(mx, 4));
    float se = __expf(v.x - mx) + __expf(v.y - mx)
             + __expf(v.z - mx) + __expf(v.w - mx);
    se += __shfl_xor(se, 1);
    se += __shfl_xor(se, 2);
    se += __shfl_xor(se, 4);
    float ls = __logf(se);
    v.x = v.x - mx - ls; v.y = v.y - mx - ls;
    v.z = v.z - mx - ls; v.w = v.w - mx - ls;
    if (ej == 0)
        *reinterpret_cast<float4*>(out + (size_t)n * 32 + cg * 4) = v;
}

// ---------------- launch ----------------

extern "C" void kernel_launch(void* const* d_in, const int* in_sizes, int n_in,
                              void* d_out, int out_size, void* d_ws, size_t ws_size,
                              hipStream_t stream) {
    (void)in_sizes; (void)n_in; (void)out_size; (void)ws_size;
    const float* x    = (const float*)d_in[0];
    const int*   ei   = (const int*)d_in[1];
    const float* W1l  = (const float*)d_in[2];
    const float* W1r  = (const float*)d_in[3];
    const float* att1 = (const float*)d_in[4];
    const float* b1   = (const float*)d_in[5];
    const float* W2l  = (const float*)d_in[6];
    const float* W2r  = (const float*)d_in[7];
    const float* att2 = (const float*)d_in[8];
    const float* b2   = (const float*)d_in[9];
    float* outp = (float*)d_out;

    char* ws = (char*)d_ws;
    size_t o = 0;
    auto alloc = [&](size_t bytes) {
        char* p = ws + o;
        o = (o + bytes + 255) & ~(size_t)255;
        return p;
    };
    unsigned short* xl1b = (unsigned short*)alloc((size_t)N_NODES * 512 * 2);
    float* xr1    = (float*)alloc((size_t)N_NODES * 512 * 4);
    float* h1     = (float*)alloc((size_t)N_NODES * 512 * 4);
    float* xw2    = (float*)alloc((size_t)N_NODES * 64 * 4);
    unsigned short* Abf = (unsigned short*)alloc((size_t)N_NODES * 768 * 2);
    unsigned short* Bbf = (unsigned short*)alloc((size_t)1024 * 768 * 2);
    int*   deg    = (int*)alloc((size_t)N_NODES * 4);
    int*   offs   = (int*)alloc((size_t)(N_NODES + 1) * 4);
    int*   ssrc   = (int*)alloc((size_t)ET * 4);

    hipMemsetAsync(deg, 0, (size_t)N_NODES * 4, stream);

    k_prep   <<<NB_COUNT + NB_CONVX + NB_CONVW, 256, 0, stream>>>(
                 ei, deg, x, Abf, W1l, W1r, Bbf);
    k_scan   <<<1,                    1024, 0, stream>>>(deg, offs);
    k_scatter<<<(ET + 255) / 256,      256, 0, stream>>>(ei, offs, deg, ssrc);
    k_mfma1  <<<dim3(79, 8),           256, 0, stream>>>(Abf, Bbf, xl1b, xr1);
    k_node1f <<<N_NODES,               512, 0, stream>>>(offs, ssrc, xl1b, xr1, att1, b1, h1);
    k_gemm2  <<<(N_NODES + 31) / 32,   256, 0, stream>>>(h1, W2l, W2r, xw2);
    k_node2f <<<N_NODES / 4,           256, 0, stream>>>(offs, ssrc, xw2, att2, b2, outp);
}

// Round 14
// 272.387 us; speedup vs baseline: 1.5070x; 1.0671x over previous
//
#include <hip/hip_runtime.h>
#include <hip/hip_bf16.h>

// GATv2 x2 on MI355X — MFMA gemm1 (split-bf16), bf16 xl1 gather, DPP reduce.
// R14: issue-fat trim in node kernels:
//  - epilogue elu via __expf(v)-1 (expm1f was ~20 insts x8 per lane),
//  - final slot-reduce xor8 step via DPP row_ror:8 (LDS pipe -> VALU),
//  - C=16 chunks (lane owns edges ej and ej+8): half the loop iterations,
//    2x memory-level parallelism; rows prefetch +1 chunk, offsets +2.

constexpr int N_NODES = 10000;
constexpr int N_EDGES = 320000;
constexpr int ET      = N_EDGES + N_NODES;   // 330000 incl. self loops
constexpr float NEG_SLOPE = 0.2f;
constexpr int MAXD1 = 384;                   // LDS ssrc cache (layer1)
constexpr int MAXD2 = 384;                   // (layer2, 4 nodes/block)

constexpr int NB_COUNT = (ET + 255) / 256;          // 1290
constexpr int NB_CONVX = (N_NODES * 64) / 256;      // 2500
constexpr int NB_CONVW = (1024 * 64) / 256;         // 256

typedef __attribute__((ext_vector_type(8))) short short8;
typedef __attribute__((ext_vector_type(8))) unsigned short ushort8_t;
typedef __attribute__((ext_vector_type(4))) float floatx4;

__device__ __forceinline__ float lrelu(float a) {
    return fmaxf(a, NEG_SLOPE * a);
}
__device__ __forceinline__ unsigned short f2bf(float f) {   // RNE
    unsigned u = __float_as_uint(f);
    unsigned r = u + 0x7FFFu + ((u >> 16) & 1u);
    return (unsigned short)(r >> 16);
}
__device__ __forceinline__ float bf2f(unsigned short h) {
    return __uint_as_float((unsigned)h << 16);
}
// sum over each aligned group of 8 lanes, result in all 8 (pure VALU)
__device__ __forceinline__ float red8_dpp(float p) {
    int x;
    x = __builtin_amdgcn_update_dpp(0, __float_as_int(p), 0xB1, 0xF, 0xF, true);
    p += __int_as_float(x);                  // quad_perm [1,0,3,2]
    x = __builtin_amdgcn_update_dpp(0, __float_as_int(p), 0x4E, 0xF, 0xF, true);
    p += __int_as_float(x);                  // quad_perm [2,3,0,1]
    x = __builtin_amdgcn_update_dpp(0, __float_as_int(p), 0x141, 0xF, 0xF, true);
    p += __int_as_float(x);                  // row_half_mirror
    return p;
}
__device__ __forceinline__ float red8max_dpp(float p) {
    int x;
    x = __builtin_amdgcn_update_dpp(0, __float_as_int(p), 0xB1, 0xF, 0xF, true);
    p = fmaxf(p, __int_as_float(x));
    x = __builtin_amdgcn_update_dpp(0, __float_as_int(p), 0x4E, 0xF, 0xF, true);
    p = fmaxf(p, __int_as_float(x));
    x = __builtin_amdgcn_update_dpp(0, __float_as_int(p), 0x141, 0xF, 0xF, true);
    p = fmaxf(p, __int_as_float(x));
    return p;
}
// pairwise add with lane^8 partner (row_ror:8 within 16-lane rows)
__device__ __forceinline__ float ror8_add(float p) {
    int x = __builtin_amdgcn_update_dpp(0, __float_as_int(p), 0x128, 0xF, 0xF, true);
    return p + __int_as_float(x);
}

// ---------------- fused prep: deg count + conv_x + conv_w ----------------

__global__ __launch_bounds__(256) void k_prep(const int* __restrict__ ei,
        int* __restrict__ deg, const float* __restrict__ x,
        unsigned short* __restrict__ A, const float* __restrict__ Wl,
        const float* __restrict__ Wr, unsigned short* __restrict__ Bt) {
    int b = blockIdx.x, t = threadIdx.x;
    if (b < NB_COUNT) {
        int e = b * 256 + t;
        if (e >= ET) return;
        int d = (e < N_EDGES) ? ei[N_EDGES + e] : (e - N_EDGES);
        atomicAdd(&deg[d], 1);
    } else if (b < NB_COUNT + NB_CONVX) {
        int idx = (b - NB_COUNT) * 256 + t;       // < N_NODES*64
        int m = idx >> 6, kg = (idx & 63) << 2;
        float4 v = *reinterpret_cast<const float4*>(x + (size_t)m * 256 + kg);
        ushort4 hi = make_ushort4(f2bf(v.x), f2bf(v.y), f2bf(v.z), f2bf(v.w));
        ushort4 lo = make_ushort4(f2bf(v.x - bf2f(hi.x)), f2bf(v.y - bf2f(hi.y)),
                                  f2bf(v.z - bf2f(hi.z)), f2bf(v.w - bf2f(hi.w)));
        size_t base = (size_t)m * 768 + kg;
        *reinterpret_cast<ushort4*>(A + base)       = hi;
        *reinterpret_cast<ushort4*>(A + base + 256) = lo;
        *reinterpret_cast<ushort4*>(A + base + 512) = hi;
    } else {
        int idx = (b - NB_COUNT - NB_CONVX) * 256 + t;   // < 1024*64
        int n = idx >> 6, kg = (idx & 63) << 2;
        const float* src = (n < 512) ? (Wl + n) : (Wr + (n - 512));
        float v0 = src[(size_t)(kg + 0) * 512];
        float v1 = src[(size_t)(kg + 1) * 512];
        float v2 = src[(size_t)(kg + 2) * 512];
        float v3 = src[(size_t)(kg + 3) * 512];
        ushort4 hi = make_ushort4(f2bf(v0), f2bf(v1), f2bf(v2), f2bf(v3));
        ushort4 lo = make_ushort4(f2bf(v0 - bf2f(hi.x)), f2bf(v1 - bf2f(hi.y)),
                                  f2bf(v2 - bf2f(hi.z)), f2bf(v3 - bf2f(hi.w)));
        size_t base = (size_t)n * 768 + kg;
        *reinterpret_cast<ushort4*>(Bt + base)       = hi;
        *reinterpret_cast<ushort4*>(Bt + base + 256) = hi;
        *reinterpret_cast<ushort4*>(Bt + base + 512) = lo;
    }
}

// ---------------- CSR scan + scatter ----------------

__global__ __launch_bounds__(1024) void k_scan(const int* __restrict__ deg,
                                               int* __restrict__ offs) {
    __shared__ int part[1024];
    const int CH = 10;                       // ceil(10000/1024)
    int t = threadIdx.x;
    int base = t * CH;
    int loc[CH];
    int s = 0;
    for (int i = 0; i < CH; ++i) {
        int idx = base + i;
        int v = (idx < N_NODES) ? deg[idx] : 0;
        loc[i] = s; s += v;
    }
    part[t] = s;
    __syncthreads();
    for (int o = 1; o < 1024; o <<= 1) {
        int add = (t >= o) ? part[t - o] : 0;
        __syncthreads();
        part[t] += add;
        __syncthreads();
    }
    int excl = part[t] - s;
    for (int i = 0; i < CH; ++i) {
        int idx = base + i;
        if (idx < N_NODES) offs[idx] = excl + loc[i];
    }
    if (t == 1023) offs[N_NODES] = part[1023];
}

// deg doubles as countdown cursor: pos = offs[d] + (--deg[d])
__global__ void k_scatter(const int* __restrict__ ei, const int* __restrict__ offs,
                          int* __restrict__ deg, int* __restrict__ ssrc) {
    int e = blockIdx.x * 256 + threadIdx.x;
    if (e >= ET) return;
    int s, d;
    if (e < N_EDGES) { s = ei[e]; d = ei[N_EDGES + e]; }
    else             { s = d = e - N_EDGES; }
    int pos = offs[d] + atomicAdd(&deg[d], -1) - 1;
    ssrc[pos] = s;
}

// ---------------- layer 1 MFMA GEMM ----------------

// 128x128 tile, M=10000 N=1024 K=768, grid (79,8), 4 waves/block.
__global__ __launch_bounds__(256) void k_mfma1(const unsigned short* __restrict__ A,
        const unsigned short* __restrict__ Bt, unsigned short* __restrict__ xl1b,
        float* __restrict__ xr1) {
    __shared__ unsigned short As[128 * 40];   // stride 40: 2-way max = free
    __shared__ unsigned short Bs[128 * 40];
    int t = threadIdx.x;
    int wave = t >> 6, L = t & 63;
    int wm = wave & 1, wn = wave >> 1;
    int row0 = blockIdx.x * 128, n0 = blockIdx.y * 128;
    int q = L >> 4, rr = L & 15;
    floatx4 acc[4][4];
#pragma unroll
    for (int i = 0; i < 4; ++i)
#pragma unroll
        for (int j = 0; j < 4; ++j) acc[i][j] = (floatx4){0.f, 0.f, 0.f, 0.f};
    int ra = t >> 2,        ka = (t & 3) * 8;
    int rb = (t + 256) >> 2, kb = ((t + 256) & 3) * 8;
    int gma = row0 + ra; gma = (gma < N_NODES) ? gma : (N_NODES - 1);
    int gmb = row0 + rb; gmb = (gmb < N_NODES) ? gmb : (N_NODES - 1);
    for (int kc = 0; kc < 768; kc += 32) {
        __syncthreads();
        *reinterpret_cast<uint4*>(&As[ra * 40 + ka]) =
            *reinterpret_cast<const uint4*>(A + (size_t)gma * 768 + kc + ka);
        *reinterpret_cast<uint4*>(&As[rb * 40 + kb]) =
            *reinterpret_cast<const uint4*>(A + (size_t)gmb * 768 + kc + kb);
        *reinterpret_cast<uint4*>(&Bs[ra * 40 + ka]) =
            *reinterpret_cast<const uint4*>(Bt + (size_t)(n0 + ra) * 768 + kc + ka);
        *reinterpret_cast<uint4*>(&Bs[rb * 40 + kb]) =
            *reinterpret_cast<const uint4*>(Bt + (size_t)(n0 + rb) * 768 + kc + kb);
        __syncthreads();
        short8 af[4], bf[4];
#pragma unroll
        for (int st = 0; st < 4; ++st)
            af[st] = *reinterpret_cast<const short8*>(
                &As[(wm * 64 + st * 16 + rr) * 40 + q * 8]);
#pragma unroll
        for (int st = 0; st < 4; ++st)
            bf[st] = *reinterpret_cast<const short8*>(
                &Bs[(wn * 64 + st * 16 + rr) * 40 + q * 8]);
#pragma unroll
        for (int i = 0; i < 4; ++i)
#pragma unroll
            for (int j = 0; j < 4; ++j)
                acc[i][j] = __builtin_amdgcn_mfma_f32_16x16x32_bf16(
                    af[i], bf[j], acc[i][j], 0, 0, 0);
    }
    // epilogue: C/D layout col=lane&15, row=(lane>>4)*4+reg  [m89/m91]
#pragma unroll
    for (int j = 0; j < 4; ++j) {
        int gc = n0 + wn * 64 + j * 16 + rr;
        if (gc < 512) {
#pragma unroll
            for (int i = 0; i < 4; ++i)
#pragma unroll
                for (int r = 0; r < 4; ++r) {
                    int gr = row0 + wm * 64 + i * 16 + q * 4 + r;
                    if (gr < N_NODES)
                        xl1b[(size_t)gr * 512 + gc] = f2bf(acc[i][j][r]);
                }
        } else {
            int col = gc - 512;
#pragma unroll
            for (int i = 0; i < 4; ++i)
#pragma unroll
                for (int r = 0; r < 4; ++r) {
                    int gr = row0 + wm * 64 + i * 16 + q * 4 + r;
                    if (gr < N_NODES)
                        xr1[(size_t)gr * 512 + col] = acc[i][j][r];
                }
        }
    }
}

// Fused edge+node layer 1: one block (512 thr = 8 waves) per node; wave = head.
// C=16: lane (ej,cg) owns edges base+ej and base+8+ej, channels cg*8..+7.
__global__ __launch_bounds__(512) void k_node1f(const int* __restrict__ offs,
        const int* __restrict__ ssrc, const unsigned short* __restrict__ xl1b,
        const float* __restrict__ xr1, const float* __restrict__ att1,
        const float* __restrict__ b1, float* __restrict__ h1) {
    constexpr int C = 16;
    __shared__ int slds[MAXD1];          // BYTE offsets (sj * 1024)
    int n = blockIdx.x;
    int t = threadIdx.x;
    int h = t >> 6, lane = t & 63;
    int beg = offs[n], dcnt = offs[n + 1] - beg;
    int cap = (dcnt < MAXD1) ? dcnt : MAXD1;
    for (int i = t; i < cap; i += 512) slds[i] = ssrc[beg + i] << 10;
    __syncthreads();
    int ej = lane >> 3;                  // edge slot
    int cg = lane & 7;                   // channel group of 8
    float xrv[8], atv[8];
    {
        const float* xrrow = xr1 + (size_t)n * 512 + h * 64 + cg * 8;
        const float* atrow = att1 + h * 64 + cg * 8;
        float4 a0 = *reinterpret_cast<const float4*>(xrrow);
        float4 a1 = *reinterpret_cast<const float4*>(xrrow + 4);
        float4 c0 = *reinterpret_cast<const float4*>(atrow);
        float4 c1 = *reinterpret_cast<const float4*>(atrow + 4);
        xrv[0]=a0.x; xrv[1]=a0.y; xrv[2]=a0.z; xrv[3]=a0.w;
        xrv[4]=a1.x; xrv[5]=a1.y; xrv[6]=a1.z; xrv[7]=a1.w;
        atv[0]=c0.x; atv[1]=c0.y; atv[2]=c0.z; atv[3]=c0.w;
        atv[4]=c1.x; atv[5]=c1.y; atv[6]=c1.z; atv[7]=c1.w;
    }
    float l = 0.f;
    float acc8[8];
#pragma unroll
    for (int i = 0; i < 8; ++i) acc8[i] = 0.f;
    const char* xlbase = reinterpret_cast<const char*>(xl1b) + h * 128 + cg * 16;

    if (dcnt <= MAXD1) {
        // ---- fast path (always taken: max degree << MAXD1) ----
        auto ld_off = [&](int i1) -> int {
            int i1c = (i1 < dcnt) ? i1 : (dcnt - 1);
            return slds[i1c];
        };
        auto ld_row = [&](int off) -> ushort8_t {
            return *reinterpret_cast<const ushort8_t*>(xlbase + off);
        };
        ushort8_t uA = ld_row(ld_off(ej));
        ushort8_t uB = ld_row(ld_off(8 + ej));
        int oA1 = ld_off(16 + ej), oB1 = ld_off(24 + ej);
        for (int base = 0; base < dcnt; base += C) {
            ushort8_t uA1 = ld_row(oA1), uB1 = ld_row(oB1);   // rows +1 chunk
            int oA2 = ld_off(base + 32 + ej);                 // offs +2 chunks
            int oB2 = ld_off(base + 40 + ej);
            float xsA[8], xsB[8];
#pragma unroll
            for (int i = 0; i < 8; ++i) { xsA[i] = bf2f(uA[i]); xsB[i] = bf2f(uB[i]); }
            float pA0 = 0.f, pA1 = 0.f, pB0 = 0.f, pB1 = 0.f;
#pragma unroll
            for (int i = 0; i < 4; ++i) {
                pA0 += lrelu(xsA[i] + xrv[i]) * atv[i];
                pA1 += lrelu(xsA[i + 4] + xrv[i + 4]) * atv[i + 4];
                pB0 += lrelu(xsB[i] + xrv[i]) * atv[i];
                pB1 += lrelu(xsB[i + 4] + xrv[i + 4]) * atv[i + 4];
            }
            float pA = red8_dpp(pA0 + pA1);
            float pB = red8_dpp(pB0 + pB1);
            if (base + ej >= dcnt)     pA = -1e30f;
            if (base + 8 + ej >= dcnt) pB = -1e30f;
            float wA = __expf(fminf(pA, 60.f));
            float wB = __expf(fminf(pB, 60.f));
            l += wA + wB;
#pragma unroll
            for (int i = 0; i < 8; ++i) acc8[i] += wA * xsA[i] + wB * xsB[i];
            uA = uA1; uB = uB1; oA1 = oA2; oB1 = oB2;
        }
    } else {
        // ---- slow path (theoretical only) ----
        for (int base = 0; base < dcnt; base += 8) {
            int i1 = base + ej;
            int i1c = (i1 < dcnt) ? i1 : (dcnt - 1);
            int off = (i1c < MAXD1) ? slds[i1c] : (ssrc[beg + i1c] << 10);
            ushort8_t u = *reinterpret_cast<const ushort8_t*>(xlbase + off);
            float xs[8];
#pragma unroll
            for (int i = 0; i < 8; ++i) xs[i] = bf2f(u[i]);
            float p0 = 0.f, p1 = 0.f;
#pragma unroll
            for (int i = 0; i < 4; ++i) {
                p0 += lrelu(xs[i] + xrv[i]) * atv[i];
                p1 += lrelu(xs[i + 4] + xrv[i + 4]) * atv[i + 4];
            }
            float p = red8_dpp(p0 + p1);
            if (base + ej >= dcnt) p = -1e30f;
            float w = __expf(fminf(p, 60.f));
            l += w;
#pragma unroll
            for (int i = 0; i < 8; ++i) acc8[i] += w * xs[i];
        }
    }
    // reduce over the 8 edge slots: DPP ror8 + swizzle xor16/32
    l = ror8_add(l); l += __shfl_xor(l, 16); l += __shfl_xor(l, 32);
#pragma unroll
    for (int i = 0; i < 8; ++i) {
        acc8[i] = ror8_add(acc8[i]);
        acc8[i] += __shfl_xor(acc8[i], 16);
        acc8[i] += __shfl_xor(acc8[i], 32);
    }
    float inv = 1.f / (l + 1e-16f);
    float v8[8];
    {
        const float* brow = b1 + h * 64 + cg * 8;
#pragma unroll
        for (int i = 0; i < 8; ++i) {
            float v = acc8[i] * inv + brow[i];
            v8[i] = (v > 0.f) ? v : (__expf(v) - 1.f);   // elu (fast exp)
        }
    }
    if (ej == 0) {
        float4 va = {v8[0], v8[1], v8[2], v8[3]};
        float4 vb = {v8[4], v8[5], v8[6], v8[7]};
        float* dst = h1 + (size_t)n * 512 + h * 64 + cg * 8;
        *reinterpret_cast<float4*>(dst)     = va;
        *reinterpret_cast<float4*>(dst + 4) = vb;
    }
}

// ---------------- layer 2 ----------------

// 32 rows x 64 cols per block, 256 thr = 4 waves; wave owns 8 rows.
__global__ __launch_bounds__(256) void k_gemm2(const float* __restrict__ h1,
        const float* __restrict__ Wl, const float* __restrict__ Wr,
        float* __restrict__ xw2) {
    __shared__ float hs[32 * 512];       // 64 KB
    int t = threadIdx.x;
    int wave = t >> 6, j = t & 63;
    int n0 = blockIdx.x * 32;
    {
        float4* hdst = reinterpret_cast<float4*>(hs);
        for (int i = t; i < 32 * 128; i += 256) {
            int rrow = i >> 7;
            int grow = n0 + rrow;
            grow = (grow < N_NODES) ? grow : (N_NODES - 1);
            hdst[i] = reinterpret_cast<const float4*>(
                          h1 + (size_t)grow * 512)[i & 127];
        }
    }
    __syncthreads();
    const float* W = (j < 32) ? (Wl + j) : (Wr + (j - 32));
    float acc[8];
#pragma unroll
    for (int r = 0; r < 8; ++r) acc[r] = 0.f;
    for (int k = 0; k < 512; k += 4) {
        float w0 = W[(size_t)(k + 0) * 32];
        float w1 = W[(size_t)(k + 1) * 32];
        float w2 = W[(size_t)(k + 2) * 32];
        float w3 = W[(size_t)(k + 3) * 32];
#pragma unroll
        for (int r = 0; r < 8; ++r) {
            float4 a = *reinterpret_cast<const float4*>(
                &hs[(wave * 8 + r) * 512 + k]);
            acc[r] += a.x * w0 + a.y * w1 + a.z * w2 + a.w * w3;
        }
    }
#pragma unroll
    for (int r = 0; r < 8; ++r) {
        int grow = n0 + wave * 8 + r;
        if (grow < N_NODES) xw2[(size_t)grow * 64 + j] = acc[r];
    }
}

// Fused edge+node layer 2 + log_softmax: one wave per node (4 nodes/block).
// C=16: lane (ej,cg) owns edges base+ej, base+8+ej; channels cg*4..+3.
__global__ __launch_bounds__(256) void k_node2f(const int* __restrict__ offs,
        const int* __restrict__ ssrc, const float* __restrict__ xw2,
        const float* __restrict__ att2, const float* __restrict__ b2,
        float* __restrict__ out) {
    constexpr int C = 16;
    __shared__ int slds[4 * MAXD2];      // BYTE offsets (sj * 256)
    int t = threadIdx.x;
    int wv = t >> 6;
    int n = blockIdx.x * 4 + wv;
    int lane = t & 63;
    int beg = offs[n], dcnt = offs[n + 1] - beg;
    int cap = (dcnt < MAXD2) ? dcnt : MAXD2;
    int* sl = slds + wv * MAXD2;
    for (int i = lane; i < cap; i += 64) sl[i] = ssrc[beg + i] << 8;
    __syncthreads();
    int ej = lane >> 3;
    int cg = lane & 7;
    float4 xr = *reinterpret_cast<const float4*>(xw2 + (size_t)n * 64 + 32 + cg * 4);
    float4 at = *reinterpret_cast<const float4*>(att2 + cg * 4);
    float l = 0.f;
    float4 ac = {0.f, 0.f, 0.f, 0.f};
    const char* xwbase = reinterpret_cast<const char*>(xw2) + cg * 16;

    if (dcnt <= MAXD2) {
        auto ld_off = [&](int i1) -> int {
            int i1c = (i1 < dcnt) ? i1 : (dcnt - 1);
            return sl[i1c];
        };
        auto ld_row = [&](int off) -> float4 {
            return *reinterpret_cast<const float4*>(xwbase + off);
        };
        float4 uA = ld_row(ld_off(ej));
        float4 uB = ld_row(ld_off(8 + ej));
        int oA1 = ld_off(16 + ej), oB1 = ld_off(24 + ej);
        for (int base = 0; base < dcnt; base += C) {
            float4 uA1 = ld_row(oA1), uB1 = ld_row(oB1);
            int oA2 = ld_off(base + 32 + ej);
            int oB2 = ld_off(base + 40 + ej);
            float pA0 = lrelu(uA.x + xr.x) * at.x + lrelu(uA.z + xr.z) * at.z;
            float pA1 = lrelu(uA.y + xr.y) * at.y + lrelu(uA.w + xr.w) * at.w;
            float pB0 = lrelu(uB.x + xr.x) * at.x + lrelu(uB.z + xr.z) * at.z;
            float pB1 = lrelu(uB.y + xr.y) * at.y + lrelu(uB.w + xr.w) * at.w;
            float pA = red8_dpp(pA0 + pA1);
            float pB = red8_dpp(pB0 + pB1);
            if (base + ej >= dcnt)     pA = -1e30f;
            if (base + 8 + ej >= dcnt) pB = -1e30f;
            float wA = __expf(fminf(pA, 60.f));
            float wB = __expf(fminf(pB, 60.f));
            l += wA + wB;
            ac.x += wA * uA.x + wB * uB.x;
            ac.y += wA * uA.y + wB * uB.y;
            ac.z += wA * uA.z + wB * uB.z;
            ac.w += wA * uA.w + wB * uB.w;
            uA = uA1; uB = uB1; oA1 = oA2; oB1 = oB2;
        }
    } else {
        for (int base = 0; base < dcnt; base += 8) {
            int i1 = base + ej;
            int i1c = (i1 < dcnt) ? i1 : (dcnt - 1);
            int off = (i1c < MAXD2) ? sl[i1c] : (ssrc[beg + i1c] << 8);
            float4 u0 = *reinterpret_cast<const float4*>(xwbase + off);
            float p0 = lrelu(u0.x + xr.x) * at.x + lrelu(u0.z + xr.z) * at.z;
            float p1 = lrelu(u0.y + xr.y) * at.y + lrelu(u0.w + xr.w) * at.w;
            float p = red8_dpp(p0 + p1);
            if (base + ej >= dcnt) p = -1e30f;
            float w = __expf(fminf(p, 60.f));
            l += w;
            ac.x += w * u0.x; ac.y += w * u0.y;
            ac.z += w * u0.z; ac.w += w * u0.w;
        }
    }
    l = ror8_add(l); l += __shfl_xor(l, 16); l += __shfl_xor(l, 32);
    ac.x = ror8_add(ac.x); ac.x += __shfl_xor(ac.x, 16); ac.x += __shfl_xor(ac.x, 32);
    ac.y = ror8_add(ac.y); ac.y += __shfl_xor(ac.y, 16); ac.y += __shfl_xor(ac.y, 32);
    ac.z = ror8_add(ac.z); ac.z += __shfl_xor(ac.z, 16); ac.z += __shfl_xor(ac.z, 32);
    ac.w = ror8_add(ac.w); ac.w += __shfl_xor(ac.w, 16); ac.w += __shfl_xor(ac.w, 32);
    float inv = 1.f / (l + 1e-16f);
    float4 bb = *reinterpret_cast<const float4*>(b2 + cg * 4);
    float4 v;
    v.x = ac.x * inv + bb.x; v.y = ac.y * inv + bb.y;
    v.z = ac.z * inv + bb.z; v.w = ac.w * inv + bb.w;
    // log_softmax over 32 channels (DPP 8-lane reduces; ej groups identical)
    float mx = red8max_dpp(fmaxf(fmaxf(v.x, v.y), fmaxf(v.z, v.w)));
    float se = red8_dpp(__expf(v.x - mx) + __expf(v.y - mx)
                      + __expf(v.z - mx) + __expf(v.w - mx));
    float ls = __logf(se);
    v.x = v.x - mx - ls; v.y = v.y - mx - ls;
    v.z = v.z - mx - ls; v.w = v.w - mx - ls;
    if (ej == 0)
        *reinterpret_cast<float4*>(out + (size_t)n * 32 + cg * 4) = v;
}

// ---------------- launch ----------------

extern "C" void kernel_launch(void* const* d_in, const int* in_sizes, int n_in,
                              void* d_out, int out_size, void* d_ws, size_t ws_size,
                              hipStream_t stream) {
    (void)in_sizes; (void)n_in; (void)out_size; (void)ws_size;
    const float* x    = (const float*)d_in[0];
    const int*   ei   = (const int*)d_in[1];
    const float* W1l  = (const float*)d_in[2];
    const float* W1r  = (const float*)d_in[3];
    const float* att1 = (const float*)d_in[4];
    const float* b1   = (const float*)d_in[5];
    const float* W2l  = (const float*)d_in[6];
    const float* W2r  = (const float*)d_in[7];
    const float* att2 = (const float*)d_in[8];
    const float* b2   = (const float*)d_in[9];
    float* outp = (float*)d_out;

    char* ws = (char*)d_ws;
    size_t o = 0;
    auto alloc = [&](size_t bytes) {
        char* p = ws + o;
        o = (o + bytes + 255) & ~(size_t)255;
        return p;
    };
    unsigned short* xl1b = (unsigned short*)alloc((size_t)N_NODES * 512 * 2);
    float* xr1    = (float*)alloc((size_t)N_NODES * 512 * 4);
    float* h1     = (float*)alloc((size_t)N_NODES * 512 * 4);
    float* xw2    = (float*)alloc((size_t)N_NODES * 64 * 4);
    unsigned short* Abf = (unsigned short*)alloc((size_t)N_NODES * 768 * 2);
    unsigned short* Bbf = (unsigned short*)alloc((size_t)1024 * 768 * 2);
    int*   deg    = (int*)alloc((size_t)N_NODES * 4);
    int*   offs   = (int*)alloc((size_t)(N_NODES + 1) * 4);
    int*   ssrc   = (int*)alloc((size_t)ET * 4);

    hipMemsetAsync(deg, 0, (size_t)N_NODES * 4, stream);

    k_prep   <<<NB_COUNT + NB_CONVX + NB_CONVW, 256, 0, stream>>>(
                 ei, deg, x, Abf, W1l, W1r, Bbf);
    k_scan   <<<1,                    1024, 0, stream>>>(deg, offs);
    k_scatter<<<(ET + 255) / 256,      256, 0, stream>>>(ei, offs, deg, ssrc);
    k_mfma1  <<<dim3(79, 8),           256, 0, stream>>>(Abf, Bbf, xl1b, xr1);
    k_node1f <<<N_NODES,               512, 0, stream>>>(offs, ssrc, xl1b, xr1, att1, b1, h1);
    k_gemm2  <<<(N_NODES + 31) / 32,   256, 0, stream>>>(h1, W2l, W2r, xw2);
    k_node2f <<<N_NODES / 4,           256, 0, stream>>>(offs, ssrc, xw2, att2, b2, outp);
}